// Round 2
// baseline (820.079 us; speedup 1.0000x reference)
//
#include <hip/hip_runtime.h>
#include <stdint.h>

#define BB 64
#define NN 4096
#define DD 256
#define SS 8
#define NITER 3
#define EPS_LN 1e-5f
#define EPS_ATTN 1e-8f

typedef __attribute__((ext_vector_type(4))) float fvec4;
typedef __attribute__((ext_vector_type(8))) __bf16 bf16x8;
typedef __attribute__((ext_vector_type(8))) unsigned short usvec8;
typedef __attribute__((ext_vector_type(4))) unsigned short usvec4;

__device__ __forceinline__ float bf2f(unsigned short u) {
  return __uint_as_float(((unsigned)u) << 16);
}
__device__ __forceinline__ unsigned short f2bf(float f) {
  unsigned u = __float_as_uint(f);
  u += 0x7FFFu + ((u >> 16) & 1u);
  return (unsigned short)(u >> 16);
}
__device__ __forceinline__ void async_copy16(void* ldsp, const void* gp) {
  __builtin_amdgcn_global_load_lds(
      (const __attribute__((address_space(1))) unsigned int*)gp,
      (__attribute__((address_space(3))) unsigned int*)ldsp, 16, 0, 0);
}

// ---------------- init: slots broadcast ----------------
__global__ void k_sinit(const float* __restrict__ slots_init, float* __restrict__ slots) {
  int b = blockIdx.x, t = threadIdx.x;
  const fvec4* src = (const fvec4*)slots_init;
  fvec4* dst = (fvec4*)(slots + (size_t)b * SS * DD);
  for (int j = t; j < SS * DD / 4; j += 256) dst[j] = src[j];
}

// ---------------- init: wkv_t[c][k] = bf16( c<256 ? Wk[k][c] : Wv[k][c-256] ) ----------------
__global__ void k_wprep(const float* __restrict__ Wk, const float* __restrict__ Wv,
                        unsigned short* __restrict__ wkv) {
  int c = blockIdx.x, t = threadIdx.x;
  const float* W = (c < DD) ? Wk : Wv;
  int cc = c & (DD - 1);
  int k = t * 4;
  usvec4 o;
  o[0] = f2bf(W[(k + 0) * DD + cc]);
  o[1] = f2bf(W[(k + 1) * DD + cc]);
  o[2] = f2bf(W[(k + 2) * DD + cc]);
  o[3] = f2bf(W[(k + 3) * DD + cc]);
  *(usvec4*)&wkv[c * DD + k] = o;
}

// ---------------- A1: x = LN(inputs)*g+b -> bf16 ----------------
__launch_bounds__(256)
__global__ void k_ln_in(const float* __restrict__ in, const float* __restrict__ g,
                        const float* __restrict__ bt, unsigned short* __restrict__ xbf) {
  int t = threadIdx.x;
  long row = (long)blockIdx.x * 32 + (t >> 3);
  int sub = t & 7;
  const float* rp = in + row * DD + sub * 32;
  fvec4 v[8];
  float s = 0.f, s2 = 0.f;
#pragma unroll
  for (int j = 0; j < 8; j++) {
    v[j] = *(const fvec4*)(rp + j * 4);
    s += v[j].x + v[j].y + v[j].z + v[j].w;
    s2 += v[j].x * v[j].x + v[j].y * v[j].y + v[j].z * v[j].z + v[j].w * v[j].w;
  }
  s += __shfl_xor(s, 1); s2 += __shfl_xor(s2, 1);
  s += __shfl_xor(s, 2); s2 += __shfl_xor(s2, 2);
  s += __shfl_xor(s, 4); s2 += __shfl_xor(s2, 4);
  float mu = s / DD;
  float rs = rsqrtf(s2 / DD - mu * mu + EPS_LN);
  unsigned short o[32];
#pragma unroll
  for (int j = 0; j < 8; j++) {
    fvec4 gg = *(const fvec4*)(g + sub * 32 + j * 4);
    fvec4 bb = *(const fvec4*)(bt + sub * 32 + j * 4);
    o[j * 4 + 0] = f2bf((v[j].x - mu) * rs * gg.x + bb.x);
    o[j * 4 + 1] = f2bf((v[j].y - mu) * rs * gg.y + bb.y);
    o[j * 4 + 2] = f2bf((v[j].z - mu) * rs * gg.z + bb.z);
    o[j * 4 + 3] = f2bf((v[j].w - mu) * rs * gg.w + bb.w);
  }
  usvec8* op = (usvec8*)(xbf + row * DD + sub * 32);
#pragma unroll
  for (int j2 = 0; j2 < 4; j2++) {
    usvec8 u;
#pragma unroll
    for (int e = 0; e < 8; e++) u[e] = o[j2 * 8 + e];
    op[j2] = u;
  }
}

// ---------------- A2: 128x256-tile GEMM, swizzled LDS, coalesced epilogue ----------------
__launch_bounds__(512, 2)
__global__ void k_gemm_kv(const unsigned short* __restrict__ xbf,
                          const unsigned short* __restrict__ wkv,
                          const float* __restrict__ bk, const float* __restrict__ bv,
                          unsigned short* __restrict__ kout, unsigned short* __restrict__ vout) {
  __shared__ __attribute__((aligned(16))) unsigned short lds[24576];  // 48 KB
  unsigned short* lA = lds;          // [128][64] swizzled
  unsigned short* lB = lds + 8192;   // [256][64] swizzled
  int t = threadIdx.x;
  int w = t >> 6, lane = t & 63;
  int wr = w >> 2, wc = w & 3;       // 2 x 4 wave grid, each 64x64 out
  int bn = blockIdx.x;               // 0 -> k, 1 -> v  (fastest: A-tile L3 reuse)
  long bm = blockIdx.y;
  const unsigned short* abase = xbf + (bm * 128) * DD;
  const unsigned short* bbase = wkv + ((long)bn * 256) * DD;
  int cl15 = lane & 15, rg = lane >> 4;
  fvec4 acc[4][4] = {};
  for (int k0 = 0; k0 < DD; k0 += 64) {
    __syncthreads();
#pragma unroll
    for (int j = 0; j < 2; j++) {
      int ca = (w * 2 + j) * 64 + lane;
      int row = ca >> 3, c16 = ca & 7;
      async_copy16(&lA[(w * 2 + j) * 512],
                   abase + (long)row * DD + k0 + ((c16 ^ (row & 7)) * 8));
    }
#pragma unroll
    for (int j = 0; j < 4; j++) {
      int cb = (w * 4 + j) * 64 + lane;
      int row = cb >> 3, c16 = cb & 7;
      async_copy16(&lB[(w * 4 + j) * 512],
                   bbase + (long)row * DD + k0 + ((c16 ^ (row & 7)) * 8));
    }
    __syncthreads();
#pragma unroll
    for (int ks = 0; ks < 2; ks++) {
      bf16x8 af[4], bfr[4];
#pragma unroll
      for (int m = 0; m < 4; m++) {
        int row = wr * 64 + m * 16 + cl15;
        int c16 = (ks * 4 + rg) ^ (row & 7);
        af[m] = *(const bf16x8*)&lA[row * 64 + c16 * 8];
      }
#pragma unroll
      for (int n = 0; n < 4; n++) {
        int row = wc * 64 + n * 16 + cl15;
        int c16 = (ks * 4 + rg) ^ (row & 7);
        bfr[n] = *(const bf16x8*)&lB[row * 64 + c16 * 8];
      }
#pragma unroll
      for (int m = 0; m < 4; m++)
#pragma unroll
        for (int n = 0; n < 4; n++)
          acc[m][n] = __builtin_amdgcn_mfma_f32_16x16x32_bf16(af[m], bfr[n], acc[m][n], 0, 0, 0);
    }
  }
  // epilogue: LDS transpose (per-wave scratch, stride 36 shorts) -> coalesced stores
  const float* bsrc = bn ? bv : bk;
  unsigned short* op = bn ? vout : kout;
  float biasv[4];
#pragma unroll
  for (int n = 0; n < 4; n++) biasv[n] = bsrc[wc * 64 + n * 16 + cl15];
  __syncthreads();  // all waves done reading lA/lB before reuse
  unsigned short* epi = &lds[w * 2304];  // 64 rows x 36 stride
#pragma unroll
  for (int h = 0; h < 2; h++) {
#pragma unroll
    for (int n2 = 0; n2 < 2; n2++) {
      int n = h * 2 + n2;
#pragma unroll
      for (int m = 0; m < 4; m++)
#pragma unroll
        for (int e = 0; e < 4; e++)
          epi[(m * 16 + rg * 4 + e) * 36 + n2 * 16 + cl15] = f2bf(acc[m][n][e] + biasv[n]);
    }
    asm volatile("s_waitcnt lgkmcnt(0)" ::: "memory");
    __builtin_amdgcn_sched_barrier(0);
    int rl = lane >> 3, u = lane & 7;
#pragma unroll
    for (int r8 = 0; r8 < 8; r8++) {
      int row_l = r8 * 8 + rl;
      usvec4 vv = *(const usvec4*)&epi[row_l * 36 + u * 4];
      *(usvec4*)&op[(bm * 128 + wr * 64 + row_l) * DD + wc * 64 + h * 32 + u * 4] = vv;
    }
    asm volatile("s_waitcnt lgkmcnt(0)" ::: "memory");
    __builtin_amdgcn_sched_barrier(0);
  }
}

// ---------------- I1: s = LN(slots); q = (s@Wq + bq) * D^-0.5 ; zero colsum ----------------
__launch_bounds__(256)
__global__ void k_slotq(const float* __restrict__ slots, const float* __restrict__ g_s,
                        const float* __restrict__ b_s, const float* __restrict__ Wq,
                        const float* __restrict__ bq, float* __restrict__ qout,
                        float* __restrict__ colsum) {
  __shared__ float sl[SS][DD];
  __shared__ float part[4][SS][64];
  int b = blockIdx.x, cg = blockIdx.y, t = threadIdx.x;
  if (cg == 0 && t < SS) colsum[b * SS + t] = 0.f;
  int row = t >> 5, seg = t & 31;
  {
    const float* sp = slots + (size_t)(b * SS + row) * DD + seg * 8;
    float v[8];
    float s = 0.f, s2 = 0.f;
#pragma unroll
    for (int e = 0; e < 8; e++) { v[e] = sp[e]; s += v[e]; s2 += v[e] * v[e]; }
#pragma unroll
    for (int m = 16; m >= 1; m >>= 1) { s += __shfl_xor(s, m); s2 += __shfl_xor(s2, m); }
    float mu = s / DD;
    float rs = rsqrtf(s2 / DD - mu * mu + EPS_LN);
#pragma unroll
    for (int e = 0; e < 8; e++) {
      int d = seg * 8 + e;
      sl[row][d] = (v[e] - mu) * rs * g_s[d] + b_s[d];
    }
  }
  __syncthreads();
  int kq = t >> 6, c = t & 63;
  int colg = cg * 64 + c;
  float a[SS] = {};
  for (int kk = 0; kk < 64; kk++) {
    int k = kq * 64 + kk;
    float wv = Wq[k * DD + colg];
#pragma unroll
    for (int i = 0; i < SS; i++) a[i] += sl[i][k] * wv;
  }
#pragma unroll
  for (int i = 0; i < SS; i++) part[kq][i][c] = a[i];
  __syncthreads();
  int i0 = t >> 6;
#pragma unroll
  for (int ii = 0; ii < 2; ii++) {
    int i = i0 + ii * 4;
    float s = part[0][i][c] + part[1][i][c] + part[2][i][c] + part[3][i][c];
    qout[(size_t)(b * SS + i) * DD + colg] = (s + bq[colg]) * 0.0625f;
  }
}

// ---------------- I2+I3 fused: dots -> slot-softmax -> colsum -> v-weighted partial updates ----------------
__launch_bounds__(256)
__global__ void k_attn(const unsigned short* __restrict__ kbf,
                       const unsigned short* __restrict__ vbf,
                       const float* __restrict__ qs, const int* __restrict__ mask,
                       float* __restrict__ colsum, float* __restrict__ upart) {
  __shared__ float ql[SS][DD];        // 8 KB
  __shared__ float aL[256 * 9];       // 9 KB, stride-9 to dodge conflicts
  __shared__ float red[4][SS][DD];    // 32 KB
  int b = blockIdx.y, t = threadIdx.x;
  int c0 = blockIdx.x * 256;
  {
    const fvec4* src = (const fvec4*)(qs + (size_t)b * SS * DD);
    fvec4* dst = (fvec4*)ql;
    for (int j = t; j < SS * DD / 4; j += 256) dst[j] = src[j];
  }
  __syncthreads();
  // phase 1: dots + per-n softmax over slots
  int n = c0 + t;
  float dots[SS] = {};
  const unsigned short* kb = kbf + ((long)b * NN + n) * DD;
  for (int d0 = 0; d0 < DD; d0 += 8) {
    usvec8 kv = *(const usvec8*)(kb + d0);
    float kf[8];
#pragma unroll
    for (int e = 0; e < 8; e++) kf[e] = bf2f(kv[e]);
#pragma unroll
    for (int i = 0; i < SS; i++) {
      fvec4 qa = *(const fvec4*)&ql[i][d0];
      fvec4 qb = *(const fvec4*)&ql[i][d0 + 4];
      dots[i] += kf[0] * qa.x + kf[1] * qa.y + kf[2] * qa.z + kf[3] * qa.w +
                 kf[4] * qb.x + kf[5] * qb.y + kf[6] * qb.z + kf[7] * qb.w;
    }
  }
  float a[SS];
  if (mask[(size_t)b * NN + n]) {
#pragma unroll
    for (int i = 0; i < SS; i++) a[i] = 0.125f;
  } else {
    float mx = dots[0];
#pragma unroll
    for (int i = 1; i < SS; i++) mx = fmaxf(mx, dots[i]);
    float sum = 0.f;
#pragma unroll
    for (int i = 0; i < SS; i++) { a[i] = __expf(dots[i] - mx); sum += a[i]; }
    float inv = 1.f / sum;
#pragma unroll
    for (int i = 0; i < SS; i++) a[i] *= inv;
  }
#pragma unroll
  for (int i = 0; i < SS; i++) aL[t * 9 + i] = a[i];
  {
    float cs[SS];
#pragma unroll
    for (int i = 0; i < SS; i++) cs[i] = a[i];
#pragma unroll
    for (int m = 32; m >= 1; m >>= 1)
#pragma unroll
      for (int i = 0; i < SS; i++) cs[i] += __shfl_xor(cs[i], m);
    if ((t & 63) == 0) {
#pragma unroll
      for (int i = 0; i < SS; i++) atomicAdd(&colsum[b * SS + i], cs[i]);
    }
  }
  __syncthreads();
  // phase 2: updates partial = sum_n a[i][n] * v[n,d]
  int d0 = (t & 31) * 8, ns = t >> 5;
  float acc[SS][8] = {};
  const unsigned short* vb = vbf + ((long)(b * NN + c0 + ns)) * DD + d0;
  for (int s8 = 0; s8 < 32; s8++) {
    int nn = s8 * 8;
    usvec8 vv = *(const usvec8*)(vb + (long)nn * DD);
    float vf[8];
#pragma unroll
    for (int e = 0; e < 8; e++) vf[e] = bf2f(vv[e]);
#pragma unroll
    for (int i = 0; i < SS; i++) {
      float aw = aL[(ns + nn) * 9 + i];
#pragma unroll
      for (int e = 0; e < 8; e++) acc[i][e] += aw * vf[e];
    }
  }
#pragma unroll
  for (int i = 0; i < SS; i++)
#pragma unroll
    for (int e = 0; e < 8; e++) acc[i][e] += __shfl_xor(acc[i][e], 32);
  int w = t >> 6, l = t & 63;
  if (l < 32) {
#pragma unroll
    for (int i = 0; i < SS; i++) {
      fvec4 a0 = {acc[i][0], acc[i][1], acc[i][2], acc[i][3]};
      fvec4 a1 = {acc[i][4], acc[i][5], acc[i][6], acc[i][7]};
      *(fvec4*)&red[w][i][l * 8] = a0;
      *(fvec4*)&red[w][i][l * 8 + 4] = a1;
    }
  }
  __syncthreads();
  int i2 = t >> 5, dsg = (t & 31) * 8;
  float* up = upart + ((size_t)(b * 16 + blockIdx.x)) * (SS * DD) + i2 * DD + dsg;
#pragma unroll
  for (int e = 0; e < 8; e++)
    up[e] = red[0][i2][dsg + e] + red[1][i2][dsg + e] + red[2][i2][dsg + e] + red[3][i2][dsg + e];
}

// ---------------- I4a: sn = slots + sum(upart)/colsum; LN -> h; h2 = relu(h@W1+b1) slice ----------------
__launch_bounds__(256)
__global__ void k_mlp1(const float* __restrict__ slots, const float* __restrict__ colsum,
                       const float* __restrict__ upart, const float* __restrict__ g_m,
                       const float* __restrict__ b_m, const float* __restrict__ W1,
                       const float* __restrict__ b1, float* __restrict__ h2g,
                       float* __restrict__ snbuf) {
  __shared__ float hL[SS][DD];
  __shared__ float part[4][SS][64];
  int b = blockIdx.x, cg = blockIdx.y, t = threadIdx.x;
  int row = t >> 5, seg = t & 31;
  {
    float inv = 1.0f / (colsum[b * SS + row] + EPS_ATTN);
    const float* sp = slots + (size_t)(b * SS + row) * DD + seg * 8;
    float u[8] = {};
    for (int c = 0; c < 16; c++) {
      const float* up = upart + ((size_t)(b * 16 + c)) * (SS * DD) + row * DD + seg * 8;
      fvec4 u0 = *(const fvec4*)up;
      fvec4 u1 = *(const fvec4*)(up + 4);
      u[0] += u0.x; u[1] += u0.y; u[2] += u0.z; u[3] += u0.w;
      u[4] += u1.x; u[5] += u1.y; u[6] += u1.z; u[7] += u1.w;
    }
    float v[8];
    float s = 0.f, s2 = 0.f;
#pragma unroll
    for (int e = 0; e < 8; e++) {
      v[e] = sp[e] + u[e] * inv;
      s += v[e]; s2 += v[e] * v[e];
    }
    if (cg == 0) {
      float* snp = snbuf + (size_t)(b * SS + row) * DD + seg * 8;
#pragma unroll
      for (int e = 0; e < 8; e++) snp[e] = v[e];
    }
#pragma unroll
    for (int m = 16; m >= 1; m >>= 1) { s += __shfl_xor(s, m); s2 += __shfl_xor(s2, m); }
    float mu = s / DD;
    float rs = rsqrtf(s2 / DD - mu * mu + EPS_LN);
#pragma unroll
    for (int e = 0; e < 8; e++) {
      int d = seg * 8 + e;
      hL[row][d] = (v[e] - mu) * rs * g_m[d] + b_m[d];
    }
  }
  __syncthreads();
  int kq = t >> 6, c = t & 63;
  int colg = cg * 64 + c;
  float a[SS] = {};
  for (int kk = 0; kk < 64; kk++) {
    int k = kq * 64 + kk;
    float wv = W1[k * DD + colg];
#pragma unroll
    for (int i = 0; i < SS; i++) a[i] += hL[i][k] * wv;
  }
#pragma unroll
  for (int i = 0; i < SS; i++) part[kq][i][c] = a[i];
  __syncthreads();
  int i0 = t >> 6;
#pragma unroll
  for (int ii = 0; ii < 2; ii++) {
    int i = i0 + ii * 4;
    float s = part[0][i][c] + part[1][i][c] + part[2][i][c] + part[3][i][c];
    h2g[(size_t)(b * SS + i) * DD + colg] = fmaxf(s + b1[colg], 0.f);
  }
}

// ---------------- I4b: slots = sn + h2@W2 + b2 (slice) ----------------
__launch_bounds__(256)
__global__ void k_mlp2(float* __restrict__ slots, const float* __restrict__ snbuf,
                       const float* __restrict__ h2g, const float* __restrict__ W2,
                       const float* __restrict__ b2) {
  __shared__ float h2L[SS][DD];
  __shared__ float part[4][SS][64];
  int b = blockIdx.x, cg = blockIdx.y, t = threadIdx.x;
  {
    const fvec4* src = (const fvec4*)(h2g + (size_t)b * SS * DD);
    fvec4* dst = (fvec4*)h2L;
    for (int j = t; j < SS * DD / 4; j += 256) dst[j] = src[j];
  }
  __syncthreads();
  int kq = t >> 6, c = t & 63;
  int colg = cg * 64 + c;
  float a[SS] = {};
  for (int kk = 0; kk < 64; kk++) {
    int k = kq * 64 + kk;
    float wv = W2[k * DD + colg];
#pragma unroll
    for (int i = 0; i < SS; i++) a[i] += h2L[i][k] * wv;
  }
#pragma unroll
  for (int i = 0; i < SS; i++) part[kq][i][c] = a[i];
  __syncthreads();
  int i0 = t >> 6;
#pragma unroll
  for (int ii = 0; ii < 2; ii++) {
    int i = i0 + ii * 4;
    float s = part[0][i][c] + part[1][i][c] + part[2][i][c] + part[3][i][c];
    size_t idx = (size_t)(b * SS + i) * DD + colg;
    slots[idx] = snbuf[idx] + s + b2[colg];
  }
}

// ---------------- final LN -> out ----------------
__launch_bounds__(256)
__global__ void k_out(const float* __restrict__ slots, const float* __restrict__ g_o,
                      const float* __restrict__ b_o, float* __restrict__ out) {
  int b = blockIdx.x, t = threadIdx.x;
  int row = t >> 5, seg = t & 31;
  const float* sp = slots + (size_t)(b * SS + row) * DD + seg * 8;
  float v[8];
  float s = 0.f, s2 = 0.f;
#pragma unroll
  for (int e = 0; e < 8; e++) { v[e] = sp[e]; s += v[e]; s2 += v[e] * v[e]; }
#pragma unroll
  for (int m = 16; m >= 1; m >>= 1) { s += __shfl_xor(s, m); s2 += __shfl_xor(s2, m); }
  float mu = s / DD;
  float rs = rsqrtf(s2 / DD - mu * mu + EPS_LN);
#pragma unroll
  for (int e = 0; e < 8; e++) {
    int d = seg * 8 + e;
    out[(size_t)(b * SS + row) * DD + d] = (v[e] - mu) * rs * g_o[d] + b_o[d];
  }
}

extern "C" void kernel_launch(void* const* d_in, const int* in_sizes, int n_in,
                              void* d_out, int out_size, void* d_ws, size_t ws_size,
                              hipStream_t stream) {
  (void)in_sizes; (void)n_in; (void)out_size; (void)ws_size;
  const float* inputs = (const float*)d_in[0];
  const int* mask = (const int*)d_in[1];
  const float* slots_init = (const float*)d_in[2];
  const float* g_in = (const float*)d_in[3];
  const float* b_in = (const float*)d_in[4];
  const float* g_s = (const float*)d_in[5];
  const float* b_s = (const float*)d_in[6];
  const float* g_m = (const float*)d_in[7];
  const float* b_m = (const float*)d_in[8];
  const float* g_o = (const float*)d_in[9];
  const float* b_o = (const float*)d_in[10];
  const float* Wq = (const float*)d_in[11];
  const float* bq = (const float*)d_in[12];
  const float* Wk = (const float*)d_in[13];
  const float* bk = (const float*)d_in[14];
  const float* Wv = (const float*)d_in[15];
  const float* bv = (const float*)d_in[16];
  const float* W1 = (const float*)d_in[17];
  const float* b1 = (const float*)d_in[18];
  const float* W2 = (const float*)d_in[19];
  const float* b2 = (const float*)d_in[20];
  float* out = (float*)d_out;

  char* ws = (char*)d_ws;
  size_t off = 0;
  auto alloc = [&](size_t bytes) -> void* {
    void* p = ws + off;
    off += (bytes + 255) & ~(size_t)255;
    return p;
  };
  unsigned short* xbf = (unsigned short*)alloc((size_t)BB * NN * DD * 2);
  unsigned short* kbf = (unsigned short*)alloc((size_t)BB * NN * DD * 2);
  unsigned short* vbf = (unsigned short*)alloc((size_t)BB * NN * DD * 2);
  unsigned short* wkv = (unsigned short*)alloc((size_t)2 * DD * DD * 2);
  float* q = (float*)alloc((size_t)BB * SS * DD * 4);
  float* slots = (float*)alloc((size_t)BB * SS * DD * 4);
  float* snbuf = (float*)alloc((size_t)BB * SS * DD * 4);
  float* h2g = (float*)alloc((size_t)BB * SS * DD * 4);
  float* upart = (float*)alloc((size_t)BB * 16 * SS * DD * 4);
  float* colsum = (float*)alloc((size_t)BB * SS * 4);

  k_sinit<<<dim3(BB), dim3(256), 0, stream>>>(slots_init, slots);
  k_wprep<<<dim3(2 * DD), dim3(64), 0, stream>>>(Wk, Wv, wkv);
  k_ln_in<<<dim3(BB * NN / 32), dim3(256), 0, stream>>>(inputs, g_in, b_in, xbf);
  k_gemm_kv<<<dim3(2, BB * NN / 128), dim3(512), 0, stream>>>(xbf, wkv, bk, bv, kbf, vbf);

  for (int it = 0; it < NITER; ++it) {
    k_slotq<<<dim3(BB, 4), dim3(256), 0, stream>>>(slots, g_s, b_s, Wq, bq, q, colsum);
    k_attn<<<dim3(NN / 256, BB), dim3(256), 0, stream>>>(kbf, vbf, q, mask, colsum, upart);
    k_mlp1<<<dim3(BB, 4), dim3(256), 0, stream>>>(slots, colsum, upart, g_m, b_m, W1, b1, h2g, snbuf);
    k_mlp2<<<dim3(BB, 4), dim3(256), 0, stream>>>(slots, snbuf, h2g, W2, b2);
  }
  k_out<<<dim3(BB), dim3(256), 0, stream>>>(slots, g_o, b_o, out);
}

// Round 3
// 706.405 us; speedup vs baseline: 1.1609x; 1.1609x over previous
//
#include <hip/hip_runtime.h>
#include <stdint.h>

#define BB 64
#define NN 4096
#define DD 256
#define SS 8
#define NITER 3
#define EPS_LN 1e-5f
#define EPS_ATTN 1e-8f

typedef __attribute__((ext_vector_type(4))) float fvec4;
typedef __attribute__((ext_vector_type(8))) __bf16 bf16x8;
typedef __attribute__((ext_vector_type(8))) unsigned short usvec8;
typedef __attribute__((ext_vector_type(4))) unsigned short usvec4;

__device__ __forceinline__ float bf2f(unsigned short u) {
  return __uint_as_float(((unsigned)u) << 16);
}
__device__ __forceinline__ unsigned short f2bf(float f) {
  unsigned u = __float_as_uint(f);
  u += 0x7FFFu + ((u >> 16) & 1u);
  return (unsigned short)(u >> 16);
}
__device__ __forceinline__ void async_copy16(void* ldsp, const void* gp) {
  __builtin_amdgcn_global_load_lds(
      (const __attribute__((address_space(1))) unsigned int*)gp,
      (__attribute__((address_space(3))) unsigned int*)ldsp, 16, 0, 0);
}

// ---------------- init: slots broadcast ----------------
__global__ void k_sinit(const float* __restrict__ slots_init, float* __restrict__ slots) {
  int b = blockIdx.x, t = threadIdx.x;
  const fvec4* src = (const fvec4*)slots_init;
  fvec4* dst = (fvec4*)(slots + (size_t)b * SS * DD);
  for (int j = t; j < SS * DD / 4; j += 256) dst[j] = src[j];
}

// ---------------- init: wkv_t[c][k] = bf16( c<256 ? Wk[k][c] : Wv[k][c-256] ) ----------------
__global__ void k_wprep(const float* __restrict__ Wk, const float* __restrict__ Wv,
                        unsigned short* __restrict__ wkv) {
  int c = blockIdx.x, t = threadIdx.x;
  const float* W = (c < DD) ? Wk : Wv;
  int cc = c & (DD - 1);
  int k = t * 4;
  usvec4 o;
  o[0] = f2bf(W[(k + 0) * DD + cc]);
  o[1] = f2bf(W[(k + 1) * DD + cc]);
  o[2] = f2bf(W[(k + 2) * DD + cc]);
  o[3] = f2bf(W[(k + 3) * DD + cc]);
  *(usvec4*)&wkv[c * DD + k] = o;
}

// ---------------- A1: x = LN(inputs)*g+b -> bf16 (coalesced 128B-line reads) ----------------
__launch_bounds__(256)
__global__ void k_ln_in(const float* __restrict__ in, const float* __restrict__ g,
                        const float* __restrict__ bt, unsigned short* __restrict__ xbf) {
  int t = threadIdx.x;
  long row = (long)blockIdx.x * 32 + (t >> 3);
  int u = t & 7;
  const float* rp = in + row * DD;
  fvec4 v[8];
  float s = 0.f, s2 = 0.f;
#pragma unroll
  for (int j = 0; j < 8; j++) {
    v[j] = *(const fvec4*)(rp + j * 32 + u * 4);
    s += v[j].x + v[j].y + v[j].z + v[j].w;
    s2 += v[j].x * v[j].x + v[j].y * v[j].y + v[j].z * v[j].z + v[j].w * v[j].w;
  }
  s += __shfl_xor(s, 1); s2 += __shfl_xor(s2, 1);
  s += __shfl_xor(s, 2); s2 += __shfl_xor(s2, 2);
  s += __shfl_xor(s, 4); s2 += __shfl_xor(s2, 4);
  float mu = s / DD;
  float rs = rsqrtf(s2 / DD - mu * mu + EPS_LN);
#pragma unroll
  for (int j = 0; j < 8; j++) {
    fvec4 gg = *(const fvec4*)(g + j * 32 + u * 4);
    fvec4 bb = *(const fvec4*)(bt + j * 32 + u * 4);
    usvec4 o;
    o[0] = f2bf((v[j].x - mu) * rs * gg.x + bb.x);
    o[1] = f2bf((v[j].y - mu) * rs * gg.y + bb.y);
    o[2] = f2bf((v[j].z - mu) * rs * gg.z + bb.z);
    o[3] = f2bf((v[j].w - mu) * rs * gg.w + bb.w);
    *(usvec4*)&xbf[row * DD + j * 32 + u * 4] = o;
  }
}

// ---------------- A2: 128x256-tile GEMM, swizzled LDS, coalesced epilogue ----------------
__launch_bounds__(512, 2)
__global__ void k_gemm_kv(const unsigned short* __restrict__ xbf,
                          const unsigned short* __restrict__ wkv,
                          const float* __restrict__ bk, const float* __restrict__ bv,
                          unsigned short* __restrict__ kout, unsigned short* __restrict__ vout) {
  __shared__ __attribute__((aligned(16))) unsigned short lds[24576];  // 48 KB
  unsigned short* lA = lds;          // [128][64] swizzled
  unsigned short* lB = lds + 8192;   // [256][64] swizzled
  int t = threadIdx.x;
  int w = t >> 6, lane = t & 63;
  int wr = w >> 2, wc = w & 3;       // 2 x 4 wave grid, each 64x64 out
  int bn = blockIdx.x;               // 0 -> k, 1 -> v  (fastest: A-tile L3 reuse)
  long bm = blockIdx.y;
  const unsigned short* abase = xbf + (bm * 128) * DD;
  const unsigned short* bbase = wkv + ((long)bn * 256) * DD;
  int cl15 = lane & 15, rg = lane >> 4;
  fvec4 acc[4][4] = {};
  for (int k0 = 0; k0 < DD; k0 += 64) {
    __syncthreads();
#pragma unroll
    for (int j = 0; j < 2; j++) {
      int ca = (w * 2 + j) * 64 + lane;
      int row = ca >> 3, c16 = ca & 7;
      async_copy16(&lA[(w * 2 + j) * 512],
                   abase + (long)row * DD + k0 + ((c16 ^ (row & 7)) * 8));
    }
#pragma unroll
    for (int j = 0; j < 4; j++) {
      int cb = (w * 4 + j) * 64 + lane;
      int row = cb >> 3, c16 = cb & 7;
      async_copy16(&lB[(w * 4 + j) * 512],
                   bbase + (long)row * DD + k0 + ((c16 ^ (row & 7)) * 8));
    }
    __syncthreads();
#pragma unroll
    for (int ks = 0; ks < 2; ks++) {
      bf16x8 af[4], bfr[4];
#pragma unroll
      for (int m = 0; m < 4; m++) {
        int row = wr * 64 + m * 16 + cl15;
        int c16 = (ks * 4 + rg) ^ (row & 7);
        af[m] = *(const bf16x8*)&lA[row * 64 + c16 * 8];
      }
#pragma unroll
      for (int n = 0; n < 4; n++) {
        int row = wc * 64 + n * 16 + cl15;
        int c16 = (ks * 4 + rg) ^ (row & 7);
        bfr[n] = *(const bf16x8*)&lB[row * 64 + c16 * 8];
      }
#pragma unroll
      for (int m = 0; m < 4; m++)
#pragma unroll
        for (int n = 0; n < 4; n++)
          acc[m][n] = __builtin_amdgcn_mfma_f32_16x16x32_bf16(af[m], bfr[n], acc[m][n], 0, 0, 0);
    }
  }
  // epilogue: LDS transpose (per-wave scratch, stride 36 shorts) -> coalesced stores
  const float* bsrc = bn ? bv : bk;
  unsigned short* op = bn ? vout : kout;
  float biasv[4];
#pragma unroll
  for (int n = 0; n < 4; n++) biasv[n] = bsrc[wc * 64 + n * 16 + cl15];
  __syncthreads();  // all waves done reading lA/lB before reuse
  unsigned short* epi = &lds[w * 2304];  // 64 rows x 36 stride
#pragma unroll
  for (int h = 0; h < 2; h++) {
#pragma unroll
    for (int n2 = 0; n2 < 2; n2++) {
      int n = h * 2 + n2;
#pragma unroll
      for (int m = 0; m < 4; m++)
#pragma unroll
        for (int e = 0; e < 4; e++)
          epi[(m * 16 + rg * 4 + e) * 36 + n2 * 16 + cl15] = f2bf(acc[m][n][e] + biasv[n]);
    }
    asm volatile("s_waitcnt lgkmcnt(0)" ::: "memory");
    __builtin_amdgcn_sched_barrier(0);
    int rl = lane >> 3, u = lane & 7;
#pragma unroll
    for (int r8 = 0; r8 < 8; r8++) {
      int row_l = r8 * 8 + rl;
      usvec4 vv = *(const usvec4*)&epi[row_l * 36 + u * 4];
      *(usvec4*)&op[(bm * 128 + wr * 64 + row_l) * DD + wc * 64 + h * 32 + u * 4] = vv;
    }
    asm volatile("s_waitcnt lgkmcnt(0)" ::: "memory");
    __builtin_amdgcn_sched_barrier(0);
  }
}

// ---------------- I1: s = LN(slots); q = (s@Wq + bq) * D^-0.5 ; zero colsum ----------------
__launch_bounds__(256)
__global__ void k_slotq(const float* __restrict__ slots, const float* __restrict__ g_s,
                        const float* __restrict__ b_s, const float* __restrict__ Wq,
                        const float* __restrict__ bq, float* __restrict__ qout,
                        float* __restrict__ colsum) {
  __shared__ float sl[SS][DD];
  __shared__ float part[4][SS][64];
  int b = blockIdx.x, cg = blockIdx.y, t = threadIdx.x;
  if (cg == 0 && t < SS) colsum[b * SS + t] = 0.f;
  int row = t >> 5, seg = t & 31;
  {
    const float* sp = slots + (size_t)(b * SS + row) * DD + seg * 8;
    float v[8];
    float s = 0.f, s2 = 0.f;
#pragma unroll
    for (int e = 0; e < 8; e++) { v[e] = sp[e]; s += v[e]; s2 += v[e] * v[e]; }
#pragma unroll
    for (int m = 16; m >= 1; m >>= 1) { s += __shfl_xor(s, m); s2 += __shfl_xor(s2, m); }
    float mu = s / DD;
    float rs = rsqrtf(s2 / DD - mu * mu + EPS_LN);
#pragma unroll
    for (int e = 0; e < 8; e++) {
      int d = seg * 8 + e;
      sl[row][d] = (v[e] - mu) * rs * g_s[d] + b_s[d];
    }
  }
  __syncthreads();
  int kq = t >> 6, c = t & 63;
  int colg = cg * 64 + c;
  float a[SS] = {};
  for (int kk = 0; kk < 64; kk++) {
    int k = kq * 64 + kk;
    float wv = Wq[k * DD + colg];
#pragma unroll
    for (int i = 0; i < SS; i++) a[i] += sl[i][k] * wv;
  }
#pragma unroll
  for (int i = 0; i < SS; i++) part[kq][i][c] = a[i];
  __syncthreads();
  int i0 = t >> 6;
#pragma unroll
  for (int ii = 0; ii < 2; ii++) {
    int i = i0 + ii * 4;
    float s = part[0][i][c] + part[1][i][c] + part[2][i][c] + part[3][i][c];
    qout[(size_t)(b * SS + i) * DD + colg] = (s + bq[colg]) * 0.0625f;
  }
}

// ---------------- I2+I3: MFMA QK^T (LDS-staged k) -> slot-softmax -> VALU PV ----------------
__launch_bounds__(256, 2)
__global__ void k_attn(const unsigned short* __restrict__ kbf,
                       const unsigned short* __restrict__ vbf,
                       const float* __restrict__ qs, const int* __restrict__ mask,
                       float* __restrict__ colsum, float* __restrict__ upart) {
  __shared__ __attribute__((aligned(16))) unsigned short kt[2][64 * 256];  // 2x32KB swizzled
  __shared__ float aL[2][64 * 9];                                          // attn weights
  int b = blockIdx.y, chunk = blockIdx.x, t = threadIdx.x;
  int w = t >> 6, lane = t & 63;
  int n_base = chunk * 256;
  int cl15 = lane & 15, hg = lane >> 4;

  // ---- q A-fragments (bf16), slots 8..15 zero ----
  bf16x8 qf[8];
  {
    int qrow = cl15 < 8 ? cl15 : 0;
    const float* qp = qs + (size_t)(b * SS + qrow) * DD;
#pragma unroll
    for (int kst = 0; kst < 8; kst++) {
      int d0 = kst * 32 + hg * 8;
      usvec8 uq;
      if (cl15 < 8) {
        fvec4 q0 = *(const fvec4*)(qp + d0);
        fvec4 q1 = *(const fvec4*)(qp + d0 + 4);
        uq[0] = f2bf(q0.x); uq[1] = f2bf(q0.y); uq[2] = f2bf(q0.z); uq[3] = f2bf(q0.w);
        uq[4] = f2bf(q1.x); uq[5] = f2bf(q1.y); uq[6] = f2bf(q1.z); uq[7] = f2bf(q1.w);
      } else {
        uq = (usvec8)0;
      }
      qf[kst] = __builtin_bit_cast(bf16x8, uq);
    }
  }

  float acc[SS][8] = {};   // PV accumulators: [slot][d-elem]
  float csum[4] = {};      // colsum partials (lanes<32)
  int ns = t >> 5, dl = (t & 31) * 8;  // phase-2 stream mapping

  // stage sub-chunk c into buf bb: wave w stages rows w*16..w*16+15 (self-staged)
  auto stage = [&](int c, int bb) {
    int r0 = n_base + c * 64;
#pragma unroll
    for (int j = 0; j < 8; j++) {
      int gidx = w * 512 + j * 64 + lane;
      int row = gidx >> 5, c16 = gidx & 31;
      async_copy16(&kt[bb][gidx * 8],
                   kbf + ((size_t)(b * NN + r0 + row)) * DD + ((c16 ^ (row & 7)) * 8));
    }
  };

  stage(0, 0);
  for (int c = 0; c < 4; c++) {
    int bb = c & 1, pb = c & 1;
    int r0 = n_base + c * 64;
    if (c < 3) {
      stage(c + 1, bb ^ 1);
      asm volatile("s_waitcnt vmcnt(8)" ::: "memory");
    } else {
      asm volatile("s_waitcnt vmcnt(0)" ::: "memory");
    }
    __builtin_amdgcn_sched_barrier(0);
    // ---- QK^T: wave w's 16-n tile (rows w*16..+15 of this sub-chunk) ----
    fvec4 S = {0.f, 0.f, 0.f, 0.f};
    int row_l = w * 16 + cl15;
#pragma unroll
    for (int kst = 0; kst < 8; kst++) {
      int c16 = (kst * 4 + hg) ^ (row_l & 7);
      bf16x8 bfk = *(const bf16x8*)&kt[bb][row_l * 256 + c16 * 8];
      S = __builtin_amdgcn_mfma_f32_16x16x32_bf16(qf[kst], bfk, S, 0, 0, 0);
    }
    // ---- per-n softmax over 8 slots (lane&15 = n, hg in {0,1} = slot half) ----
    {
      float m4 = fmaxf(fmaxf(S[0], S[1]), fmaxf(S[2], S[3]));
      float mo = __shfl_xor(m4, 16);
      float mx = fmaxf(m4, mo);
      float e0 = __expf(S[0] - mx), e1 = __expf(S[1] - mx);
      float e2 = __expf(S[2] - mx), e3 = __expf(S[3] - mx);
      float s4 = e0 + e1 + e2 + e3;
      float so = __shfl_xor(s4, 16);
      float inv = 1.f / (s4 + so);
      int mk = mask[(size_t)b * NN + r0 + row_l];
      float a0 = mk ? 0.125f : e0 * inv;
      float a1 = mk ? 0.125f : e1 * inv;
      float a2 = mk ? 0.125f : e2 * inv;
      float a3 = mk ? 0.125f : e3 * inv;
      if (lane < 32) {
        csum[0] += a0; csum[1] += a1; csum[2] += a2; csum[3] += a3;
        float* ap = &aL[pb][(w * 16 + cl15) * 9 + hg * 4];
        ap[0] = a0; ap[1] = a1; ap[2] = a2; ap[3] = a3;
      }
    }
    __syncthreads();
    // ---- phase 2: PV (coalesced global v reads, aL broadcast reads) ----
    const unsigned short* vb = vbf + ((size_t)(b * NN + r0 + ns)) * DD + dl;
#pragma unroll
    for (int s8 = 0; s8 < 8; s8++) {
      int nn = s8 * 8;
      usvec8 vv = *(const usvec8*)(vb + (size_t)nn * DD);
      float vf[8];
#pragma unroll
      for (int e = 0; e < 8; e++) vf[e] = bf2f(vv[e]);
#pragma unroll
      for (int i = 0; i < SS; i++) {
        float aw = aL[pb][(ns + nn) * 9 + i];
#pragma unroll
        for (int e = 0; e < 8; e++) acc[i][e] += aw * vf[e];
      }
    }
  }
  // ---- colsum reduce + atomics ----
#pragma unroll
  for (int m = 1; m <= 8; m <<= 1)
#pragma unroll
    for (int e = 0; e < 4; e++) csum[e] += __shfl_xor(csum[e], m);
  if (lane == 0) {
#pragma unroll
    for (int e = 0; e < 4; e++) atomicAdd(&colsum[b * SS + e], csum[e]);
  } else if (lane == 16) {
#pragma unroll
    for (int e = 0; e < 4; e++) atomicAdd(&colsum[b * SS + 4 + e], csum[e]);
  }
  // ---- cross-stream + cross-wave reduce of PV accumulators (reuse kt as scratch) ----
#pragma unroll
  for (int i = 0; i < SS; i++)
#pragma unroll
    for (int e = 0; e < 8; e++) acc[i][e] += __shfl_xor(acc[i][e], 32);
  __syncthreads();
  float* red = (float*)&kt[0][0];  // [4][SS][DD]
  if (lane < 32) {
#pragma unroll
    for (int i = 0; i < SS; i++) {
      fvec4 a0 = {acc[i][0], acc[i][1], acc[i][2], acc[i][3]};
      fvec4 a1 = {acc[i][4], acc[i][5], acc[i][6], acc[i][7]};
      *(fvec4*)&red[(w * SS + i) * DD + lane * 8] = a0;
      *(fvec4*)&red[(w * SS + i) * DD + lane * 8 + 4] = a1;
    }
  }
  __syncthreads();
  int i2 = t >> 5, dsg = (t & 31) * 8;
  float* up = upart + ((size_t)(b * 16 + chunk)) * (SS * DD) + i2 * DD + dsg;
#pragma unroll
  for (int e = 0; e < 8; e++)
    up[e] = red[(0 * SS + i2) * DD + dsg + e] + red[(1 * SS + i2) * DD + dsg + e] +
            red[(2 * SS + i2) * DD + dsg + e] + red[(3 * SS + i2) * DD + dsg + e];
}

// ---------------- I4a: sn = slots + sum(upart)/colsum; LN -> h; h2 = relu(h@W1+b1) slice ----------------
__launch_bounds__(256)
__global__ void k_mlp1(const float* __restrict__ slots, const float* __restrict__ colsum,
                       const float* __restrict__ upart, const float* __restrict__ g_m,
                       const float* __restrict__ b_m, const float* __restrict__ W1,
                       const float* __restrict__ b1, float* __restrict__ h2g,
                       float* __restrict__ snbuf) {
  __shared__ float hL[SS][DD];
  __shared__ float part[4][SS][64];
  int b = blockIdx.x, cg = blockIdx.y, t = threadIdx.x;
  int row = t >> 5, seg = t & 31;
  {
    float inv = 1.0f / (colsum[b * SS + row] + EPS_ATTN);
    const float* sp = slots + (size_t)(b * SS + row) * DD + seg * 8;
    float u[8] = {};
    for (int c = 0; c < 16; c++) {
      const float* up = upart + ((size_t)(b * 16 + c)) * (SS * DD) + row * DD + seg * 8;
      fvec4 u0 = *(const fvec4*)up;
      fvec4 u1 = *(const fvec4*)(up + 4);
      u[0] += u0.x; u[1] += u0.y; u[2] += u0.z; u[3] += u0.w;
      u[4] += u1.x; u[5] += u1.y; u[6] += u1.z; u[7] += u1.w;
    }
    float v[8];
    float s = 0.f, s2 = 0.f;
#pragma unroll
    for (int e = 0; e < 8; e++) {
      v[e] = sp[e] + u[e] * inv;
      s += v[e]; s2 += v[e] * v[e];
    }
    if (cg == 0) {
      float* snp = snbuf + (size_t)(b * SS + row) * DD + seg * 8;
#pragma unroll
      for (int e = 0; e < 8; e++) snp[e] = v[e];
    }
#pragma unroll
    for (int m = 16; m >= 1; m >>= 1) { s += __shfl_xor(s, m); s2 += __shfl_xor(s2, m); }
    float mu = s / DD;
    float rs = rsqrtf(s2 / DD - mu * mu + EPS_LN);
#pragma unroll
    for (int e = 0; e < 8; e++) {
      int d = seg * 8 + e;
      hL[row][d] = (v[e] - mu) * rs * g_m[d] + b_m[d];
    }
  }
  __syncthreads();
  int kq = t >> 6, c = t & 63;
  int colg = cg * 64 + c;
  float a[SS] = {};
  for (int kk = 0; kk < 64; kk++) {
    int k = kq * 64 + kk;
    float wv = W1[k * DD + colg];
#pragma unroll
    for (int i = 0; i < SS; i++) a[i] += hL[i][k] * wv;
  }
#pragma unroll
  for (int i = 0; i < SS; i++) part[kq][i][c] = a[i];
  __syncthreads();
  int i0 = t >> 6;
#pragma unroll
  for (int ii = 0; ii < 2; ii++) {
    int i = i0 + ii * 4;
    float s = part[0][i][c] + part[1][i][c] + part[2][i][c] + part[3][i][c];
    h2g[(size_t)(b * SS + i) * DD + colg] = fmaxf(s + b1[colg], 0.f);
  }
}

// ---------------- I4b: slots = sn + h2@W2 + b2 (slice) ----------------
__launch_bounds__(256)
__global__ void k_mlp2(float* __restrict__ slots, const float* __restrict__ snbuf,
                       const float* __restrict__ h2g, const float* __restrict__ W2,
                       const float* __restrict__ b2) {
  __shared__ float h2L[SS][DD];
  __shared__ float part[4][SS][64];
  int b = blockIdx.x, cg = blockIdx.y, t = threadIdx.x;
  {
    const fvec4* src = (const fvec4*)(h2g + (size_t)b * SS * DD);
    fvec4* dst = (fvec4*)h2L;
    for (int j = t; j < SS * DD / 4; j += 256) dst[j] = src[j];
  }
  __syncthreads();
  int kq = t >> 6, c = t & 63;
  int colg = cg * 64 + c;
  float a[SS] = {};
  for (int kk = 0; kk < 64; kk++) {
    int k = kq * 64 + kk;
    float wv = W2[k * DD + colg];
#pragma unroll
    for (int i = 0; i < SS; i++) a[i] += h2L[i][k] * wv;
  }
#pragma unroll
  for (int i = 0; i < SS; i++) part[kq][i][c] = a[i];
  __syncthreads();
  int i0 = t >> 6;
#pragma unroll
  for (int ii = 0; ii < 2; ii++) {
    int i = i0 + ii * 4;
    float s = part[0][i][c] + part[1][i][c] + part[2][i][c] + part[3][i][c];
    size_t idx = (size_t)(b * SS + i) * DD + colg;
    slots[idx] = snbuf[idx] + s + b2[colg];
  }
}

// ---------------- final LN -> out ----------------
__launch_bounds__(256)
__global__ void k_out(const float* __restrict__ slots, const float* __restrict__ g_o,
                      const float* __restrict__ b_o, float* __restrict__ out) {
  int b = blockIdx.x, t = threadIdx.x;
  int row = t >> 5, seg = t & 31;
  const float* sp = slots + (size_t)(b * SS + row) * DD + seg * 8;
  float v[8];
  float s = 0.f, s2 = 0.f;
#pragma unroll
  for (int e = 0; e < 8; e++) { v[e] = sp[e]; s += v[e]; s2 += v[e] * v[e]; }
#pragma unroll
  for (int m = 16; m >= 1; m >>= 1) { s += __shfl_xor(s, m); s2 += __shfl_xor(s2, m); }
  float mu = s / DD;
  float rs = rsqrtf(s2 / DD - mu * mu + EPS_LN);
#pragma unroll
  for (int e = 0; e < 8; e++) {
    int d = seg * 8 + e;
    out[(size_t)(b * SS + row) * DD + d] = (v[e] - mu) * rs * g_o[d] + b_o[d];
  }
}

extern "C" void kernel_launch(void* const* d_in, const int* in_sizes, int n_in,
                              void* d_out, int out_size, void* d_ws, size_t ws_size,
                              hipStream_t stream) {
  (void)in_sizes; (void)n_in; (void)out_size; (void)ws_size;
  const float* inputs = (const float*)d_in[0];
  const int* mask = (const int*)d_in[1];
  const float* slots_init = (const float*)d_in[2];
  const float* g_in = (const float*)d_in[3];
  const float* b_in = (const float*)d_in[4];
  const float* g_s = (const float*)d_in[5];
  const float* b_s = (const float*)d_in[6];
  const float* g_m = (const float*)d_in[7];
  const float* b_m = (const float*)d_in[8];
  const float* g_o = (const float*)d_in[9];
  const float* b_o = (const float*)d_in[10];
  const float* Wq = (const float*)d_in[11];
  const float* bq = (const float*)d_in[12];
  const float* Wk = (const float*)d_in[13];
  const float* bk = (const float*)d_in[14];
  const float* Wv = (const float*)d_in[15];
  const float* bv = (const float*)d_in[16];
  const float* W1 = (const float*)d_in[17];
  const float* b1 = (const float*)d_in[18];
  const float* W2 = (const float*)d_in[19];
  const float* b2 = (const float*)d_in[20];
  float* out = (float*)d_out;

  char* ws = (char*)d_ws;
  size_t off = 0;
  auto alloc = [&](size_t bytes) -> void* {
    void* p = ws + off;
    off += (bytes + 255) & ~(size_t)255;
    return p;
  };
  unsigned short* xbf = (unsigned short*)alloc((size_t)BB * NN * DD * 2);
  unsigned short* kbf = (unsigned short*)alloc((size_t)BB * NN * DD * 2);
  unsigned short* vbf = (unsigned short*)alloc((size_t)BB * NN * DD * 2);
  unsigned short* wkv = (unsigned short*)alloc((size_t)2 * DD * DD * 2);
  float* q = (float*)alloc((size_t)BB * SS * DD * 4);
  float* slots = (float*)alloc((size_t)BB * SS * DD * 4);
  float* snbuf = (float*)alloc((size_t)BB * SS * DD * 4);
  float* h2g = (float*)alloc((size_t)BB * SS * DD * 4);
  float* upart = (float*)alloc((size_t)BB * 16 * SS * DD * 4);
  float* colsum = (float*)alloc((size_t)BB * SS * 4);

  k_sinit<<<dim3(BB), dim3(256), 0, stream>>>(slots_init, slots);
  k_wprep<<<dim3(2 * DD), dim3(64), 0, stream>>>(Wk, Wv, wkv);
  k_ln_in<<<dim3(BB * NN / 32), dim3(256), 0, stream>>>(inputs, g_in, b_in, xbf);
  k_gemm_kv<<<dim3(2, BB * NN / 128), dim3(512), 0, stream>>>(xbf, wkv, bk, bv, kbf, vbf);

  for (int it = 0; it < NITER; ++it) {
    k_slotq<<<dim3(BB, 4), dim3(256), 0, stream>>>(slots, g_s, b_s, Wq, bq, q, colsum);
    k_attn<<<dim3(16, BB), dim3(256), 0, stream>>>(kbf, vbf, q, mask, colsum, upart);
    k_mlp1<<<dim3(BB, 4), dim3(256), 0, stream>>>(slots, colsum, upart, g_m, b_m, W1, b1, h2g, snbuf);
    k_mlp2<<<dim3(BB, 4), dim3(256), 0, stream>>>(slots, snbuf, h2g, W2, b2);
  }
  k_out<<<dim3(BB), dim3(256), 0, stream>>>(slots, g_o, b_o, out);
}

// Round 4
// 686.660 us; speedup vs baseline: 1.1943x; 1.0288x over previous
//
#include <hip/hip_runtime.h>
#include <stdint.h>

#define BB 64
#define NN 4096
#define DD 256
#define SS 8
#define NITER 3
#define EPS_LN 1e-5f
#define EPS_ATTN 1e-8f

typedef __attribute__((ext_vector_type(4))) float fvec4;
typedef __attribute__((ext_vector_type(8))) __bf16 bf16x8;
typedef __attribute__((ext_vector_type(8))) unsigned short usvec8;
typedef __attribute__((ext_vector_type(4))) unsigned short usvec4;

__device__ __forceinline__ float bf2f(unsigned short u) {
  return __uint_as_float(((unsigned)u) << 16);
}
__device__ __forceinline__ unsigned short f2bf(float f) {
  unsigned u = __float_as_uint(f);
  u += 0x7FFFu + ((u >> 16) & 1u);
  return (unsigned short)(u >> 16);
}
__device__ __forceinline__ void async_copy16(void* ldsp, const void* gp) {
  __builtin_amdgcn_global_load_lds(
      (const __attribute__((address_space(1))) unsigned int*)gp,
      (__attribute__((address_space(3))) unsigned int*)ldsp, 16, 0, 0);
}

// ---------------- init: slots broadcast ----------------
__global__ void k_sinit(const float* __restrict__ slots_init, float* __restrict__ slots) {
  int b = blockIdx.x, t = threadIdx.x;
  const fvec4* src = (const fvec4*)slots_init;
  fvec4* dst = (fvec4*)(slots + (size_t)b * SS * DD);
  for (int j = t; j < SS * DD / 4; j += 256) dst[j] = src[j];
}

// ---------------- init: fragment-major packed weights ----------------
// wkvf[((ct*8 + ks)*64 + lane)*8 + e] = bf16( B[col=ct*16+(lane&15)][k=ks*32+(lane>>4)*8+e] )
// where B[col][k] = (col<256 ? Wk : Wv)[k][col&255]
__global__ void k_wprepf(const float* __restrict__ Wk, const float* __restrict__ Wv,
                         unsigned short* __restrict__ wkvf) {
  int ct = blockIdx.x, ks = blockIdx.y, t = threadIdx.x;
  int col = ct * 16 + (t & 15);
  int kb = ks * 32 + (t >> 4) * 8;
  const float* W = (col < DD) ? Wk : Wv;
  int cc = col & (DD - 1);
  usvec8 o;
#pragma unroll
  for (int e = 0; e < 8; e++) o[e] = f2bf(W[(size_t)(kb + e) * DD + cc]);
  *(usvec8*)&wkvf[(((size_t)ct * 8 + ks) * 64 + t) * 8] = o;
}

// ---------------- A: fused LN + GEMM: per block 128 rows -> k,v [128][256] bf16 ----------------
__launch_bounds__(512, 2)
__global__ void k_lngemm(const float* __restrict__ in, const float* __restrict__ g,
                         const float* __restrict__ bt, const unsigned short* __restrict__ wkvf,
                         const float* __restrict__ bk, const float* __restrict__ bv,
                         unsigned short* __restrict__ kout, unsigned short* __restrict__ vout) {
  __shared__ __attribute__((aligned(16))) unsigned short lA[128 * 256];   // 64 KB swizzled
  __shared__ __attribute__((aligned(16))) unsigned short episcr[8][64 * 36];  // 36.9 KB
  int t = threadIdx.x;
  int w = t >> 6, lane = t & 63;
  int wr = w >> 2, wc = w & 3;  // 2x4 wave grid, 64 rows x 64 cols per wave per cn
  int cl15 = lane & 15, rg = lane >> 4;
  long bm = blockIdx.x;

  // ---- phase 1: LN of 128 input rows -> swizzled bf16 A-tile in LDS ----
#pragma unroll
  for (int pass = 0; pass < 2; pass++) {
    int row = pass * 64 + (t >> 3);
    int u = t & 7;
    const float* rp = in + (bm * 128 + row) * DD;
    fvec4 vv[8];
    float s = 0.f, s2 = 0.f;
#pragma unroll
    for (int j = 0; j < 8; j++) {
      vv[j] = *(const fvec4*)(rp + j * 32 + u * 4);
      s += vv[j].x + vv[j].y + vv[j].z + vv[j].w;
      s2 += vv[j].x * vv[j].x + vv[j].y * vv[j].y + vv[j].z * vv[j].z + vv[j].w * vv[j].w;
    }
    s += __shfl_xor(s, 1); s2 += __shfl_xor(s2, 1);
    s += __shfl_xor(s, 2); s2 += __shfl_xor(s2, 2);
    s += __shfl_xor(s, 4); s2 += __shfl_xor(s2, 4);
    float mu = s / DD;
    float rs = rsqrtf(s2 / DD - mu * mu + EPS_LN);
#pragma unroll
    for (int j = 0; j < 8; j++) {
      fvec4 gg = *(const fvec4*)(g + j * 32 + u * 4);
      fvec4 bb = *(const fvec4*)(bt + j * 32 + u * 4);
      usvec4 o;
      o[0] = f2bf((vv[j].x - mu) * rs * gg.x + bb.x);
      o[1] = f2bf((vv[j].y - mu) * rs * gg.y + bb.y);
      o[2] = f2bf((vv[j].z - mu) * rs * gg.z + bb.z);
      o[3] = f2bf((vv[j].w - mu) * rs * gg.w + bb.w);
      int gswz = (j * 4 + (u >> 1)) ^ (row & 7);
      *(usvec4*)&lA[row * 256 + gswz * 8 + (u & 1) * 4] = o;
    }
  }
  __syncthreads();

  // ---- phase 2: MFMA over K=256, cn=0 -> k, cn=1 -> v ----
  unsigned short* epi = &episcr[w][0];
#pragma unroll
  for (int cn = 0; cn < 2; cn++) {
    fvec4 acc[4][4] = {};
#pragma unroll
    for (int ks = 0; ks < 8; ks++) {
      bf16x8 af[4], bfr[4];
#pragma unroll
      for (int m = 0; m < 4; m++) {
        int row = wr * 64 + m * 16 + cl15;
        int gr = (ks * 4 + rg) ^ (row & 7);
        af[m] = *(const bf16x8*)&lA[row * 256 + gr * 8];
      }
#pragma unroll
      for (int n = 0; n < 4; n++) {
        int ct = cn * 16 + wc * 4 + n;
        bfr[n] = *(const bf16x8*)&wkvf[(((size_t)ct * 8 + ks) * 64 + lane) * 8];
      }
#pragma unroll
      for (int m = 0; m < 4; m++)
#pragma unroll
        for (int n = 0; n < 4; n++)
          acc[m][n] = __builtin_amdgcn_mfma_f32_16x16x32_bf16(af[m], bfr[n], acc[m][n], 0, 0, 0);
    }
    // epilogue: per-wave LDS transpose -> coalesced 64B-sector stores
    const float* bsrc = cn ? bv : bk;
    unsigned short* op = cn ? vout : kout;
    float biasv[4];
#pragma unroll
    for (int n = 0; n < 4; n++) biasv[n] = bsrc[wc * 64 + n * 16 + cl15];
#pragma unroll
    for (int h = 0; h < 2; h++) {
#pragma unroll
      for (int n2 = 0; n2 < 2; n2++) {
        int n = h * 2 + n2;
#pragma unroll
        for (int m = 0; m < 4; m++)
#pragma unroll
          for (int e = 0; e < 4; e++)
            epi[(m * 16 + rg * 4 + e) * 36 + n2 * 16 + cl15] = f2bf(acc[m][n][e] + biasv[n]);
      }
      asm volatile("s_waitcnt lgkmcnt(0)" ::: "memory");
      __builtin_amdgcn_sched_barrier(0);
      int rl = lane >> 3, u = lane & 7;
#pragma unroll
      for (int r8 = 0; r8 < 8; r8++) {
        int row_l = r8 * 8 + rl;
        usvec4 vv = *(const usvec4*)&epi[row_l * 36 + u * 4];
        *(usvec4*)&op[(bm * 128 + wr * 64 + row_l) * DD + wc * 64 + h * 32 + u * 4] = vv;
      }
      asm volatile("s_waitcnt lgkmcnt(0)" ::: "memory");
      __builtin_amdgcn_sched_barrier(0);
    }
  }
}

// ---------------- I1: s = LN(slots); q = (s@Wq + bq) * D^-0.5 ; zero colsum ----------------
__launch_bounds__(256)
__global__ void k_slotq(const float* __restrict__ slots, const float* __restrict__ g_s,
                        const float* __restrict__ b_s, const float* __restrict__ Wq,
                        const float* __restrict__ bq, float* __restrict__ qout,
                        float* __restrict__ colsum) {
  __shared__ float sl[SS][DD];
  __shared__ float part[4][SS][64];
  int b = blockIdx.x, cg = blockIdx.y, t = threadIdx.x;
  if (cg == 0 && t < SS) colsum[b * SS + t] = 0.f;
  int row = t >> 5, seg = t & 31;
  {
    const float* sp = slots + (size_t)(b * SS + row) * DD + seg * 8;
    float v[8];
    float s = 0.f, s2 = 0.f;
#pragma unroll
    for (int e = 0; e < 8; e++) { v[e] = sp[e]; s += v[e]; s2 += v[e] * v[e]; }
#pragma unroll
    for (int m = 16; m >= 1; m >>= 1) { s += __shfl_xor(s, m); s2 += __shfl_xor(s2, m); }
    float mu = s / DD;
    float rs = rsqrtf(s2 / DD - mu * mu + EPS_LN);
#pragma unroll
    for (int e = 0; e < 8; e++) {
      int d = seg * 8 + e;
      sl[row][d] = (v[e] - mu) * rs * g_s[d] + b_s[d];
    }
  }
  __syncthreads();
  int kq = t >> 6, c = t & 63;
  int colg = cg * 64 + c;
  float a[SS] = {};
  for (int kk = 0; kk < 64; kk++) {
    int k = kq * 64 + kk;
    float wv = Wq[k * DD + colg];
#pragma unroll
    for (int i = 0; i < SS; i++) a[i] += sl[i][k] * wv;
  }
#pragma unroll
  for (int i = 0; i < SS; i++) part[kq][i][c] = a[i];
  __syncthreads();
  int i0 = t >> 6;
#pragma unroll
  for (int ii = 0; ii < 2; ii++) {
    int i = i0 + ii * 4;
    float s = part[0][i][c] + part[1][i][c] + part[2][i][c] + part[3][i][c];
    qout[(size_t)(b * SS + i) * DD + colg] = (s + bq[colg]) * 0.0625f;
  }
}

// ---------------- I2+I3: MFMA QK^T (LDS-staged k) -> slot-softmax -> VALU PV ----------------
__launch_bounds__(256, 2)
__global__ void k_attn(const unsigned short* __restrict__ kbf,
                       const unsigned short* __restrict__ vbf,
                       const float* __restrict__ qs, const int* __restrict__ mask,
                       float* __restrict__ colsum, float* __restrict__ upart) {
  __shared__ __attribute__((aligned(16))) unsigned short kt[2][64 * 256];  // 2x32KB swizzled
  __shared__ float aL[2][64 * 9];                                          // attn weights
  int b = blockIdx.y, chunk = blockIdx.x, t = threadIdx.x;
  int w = t >> 6, lane = t & 63;
  int n_base = chunk * 256;
  int cl15 = lane & 15, hg = lane >> 4;

  // ---- q A-fragments (bf16), slots 8..15 zero ----
  bf16x8 qf[8];
  {
    int qrow = cl15 < 8 ? cl15 : 0;
    const float* qp = qs + (size_t)(b * SS + qrow) * DD;
#pragma unroll
    for (int kst = 0; kst < 8; kst++) {
      int d0 = kst * 32 + hg * 8;
      usvec8 uq;
      if (cl15 < 8) {
        fvec4 q0 = *(const fvec4*)(qp + d0);
        fvec4 q1 = *(const fvec4*)(qp + d0 + 4);
        uq[0] = f2bf(q0.x); uq[1] = f2bf(q0.y); uq[2] = f2bf(q0.z); uq[3] = f2bf(q0.w);
        uq[4] = f2bf(q1.x); uq[5] = f2bf(q1.y); uq[6] = f2bf(q1.z); uq[7] = f2bf(q1.w);
      } else {
        uq = (usvec8)0;
      }
      qf[kst] = __builtin_bit_cast(bf16x8, uq);
    }
  }

  float acc[SS][8] = {};   // PV accumulators: [slot][d-elem]
  float csum[4] = {};      // colsum partials (lanes<32)
  int ns = t >> 5, dl = (t & 31) * 8;  // phase-2 stream mapping

  // stage sub-chunk c into buf bb: wave w stages rows w*16..w*16+15 (self-staged)
  auto stage = [&](int c, int bb) {
    int r0 = n_base + c * 64;
#pragma unroll
    for (int j = 0; j < 8; j++) {
      int gidx = w * 512 + j * 64 + lane;
      int row = gidx >> 5, c16 = gidx & 31;
      async_copy16(&kt[bb][gidx * 8],
                   kbf + ((size_t)(b * NN + r0 + row)) * DD + ((c16 ^ (row & 7)) * 8));
    }
  };

  stage(0, 0);
  for (int c = 0; c < 4; c++) {
    int bb = c & 1, pb = c & 1;
    int r0 = n_base + c * 64;
    if (c < 3) {
      stage(c + 1, bb ^ 1);
      asm volatile("s_waitcnt vmcnt(8)" ::: "memory");
    } else {
      asm volatile("s_waitcnt vmcnt(0)" ::: "memory");
    }
    __builtin_amdgcn_sched_barrier(0);
    // ---- QK^T: wave w's 16-n tile (rows w*16..+15 of this sub-chunk) ----
    fvec4 S = {0.f, 0.f, 0.f, 0.f};
    int row_l = w * 16 + cl15;
#pragma unroll
    for (int kst = 0; kst < 8; kst++) {
      int c16 = (kst * 4 + hg) ^ (row_l & 7);
      bf16x8 bfk = *(const bf16x8*)&kt[bb][row_l * 256 + c16 * 8];
      S = __builtin_amdgcn_mfma_f32_16x16x32_bf16(qf[kst], bfk, S, 0, 0, 0);
    }
    // ---- per-n softmax over 8 slots (lane&15 = n, hg in {0,1} = slot half) ----
    {
      float m4 = fmaxf(fmaxf(S[0], S[1]), fmaxf(S[2], S[3]));
      float mo = __shfl_xor(m4, 16);
      float mx = fmaxf(m4, mo);
      float e0 = __expf(S[0] - mx), e1 = __expf(S[1] - mx);
      float e2 = __expf(S[2] - mx), e3 = __expf(S[3] - mx);
      float s4 = e0 + e1 + e2 + e3;
      float so = __shfl_xor(s4, 16);
      float inv = 1.f / (s4 + so);
      int mk = mask[(size_t)b * NN + r0 + row_l];
      float a0 = mk ? 0.125f : e0 * inv;
      float a1 = mk ? 0.125f : e1 * inv;
      float a2 = mk ? 0.125f : e2 * inv;
      float a3 = mk ? 0.125f : e3 * inv;
      if (lane < 32) {
        csum[0] += a0; csum[1] += a1; csum[2] += a2; csum[3] += a3;
        float* ap = &aL[pb][(w * 16 + cl15) * 9 + hg * 4];
        ap[0] = a0; ap[1] = a1; ap[2] = a2; ap[3] = a3;
      }
    }
    __syncthreads();
    // ---- phase 2: PV (coalesced global v reads, aL broadcast reads) ----
    const unsigned short* vb = vbf + ((size_t)(b * NN + r0 + ns)) * DD + dl;
#pragma unroll
    for (int s8 = 0; s8 < 8; s8++) {
      int nn = s8 * 8;
      usvec8 vv = *(const usvec8*)(vb + (size_t)nn * DD);
      float vf[8];
#pragma unroll
      for (int e = 0; e < 8; e++) vf[e] = bf2f(vv[e]);
#pragma unroll
      for (int i = 0; i < SS; i++) {
        float aw = aL[pb][(ns + nn) * 9 + i];
#pragma unroll
        for (int e = 0; e < 8; e++) acc[i][e] += aw * vf[e];
      }
    }
  }
  // ---- colsum reduce + atomics ----
#pragma unroll
  for (int m = 1; m <= 8; m <<= 1)
#pragma unroll
    for (int e = 0; e < 4; e++) csum[e] += __shfl_xor(csum[e], m);
  if (lane == 0) {
#pragma unroll
    for (int e = 0; e < 4; e++) atomicAdd(&colsum[b * SS + e], csum[e]);
  } else if (lane == 16) {
#pragma unroll
    for (int e = 0; e < 4; e++) atomicAdd(&colsum[b * SS + 4 + e], csum[e]);
  }
  // ---- cross-stream + cross-wave reduce of PV accumulators (reuse kt as scratch) ----
#pragma unroll
  for (int i = 0; i < SS; i++)
#pragma unroll
    for (int e = 0; e < 8; e++) acc[i][e] += __shfl_xor(acc[i][e], 32);
  __syncthreads();
  float* red = (float*)&kt[0][0];  // [4][SS][DD]
  if (lane < 32) {
#pragma unroll
    for (int i = 0; i < SS; i++) {
      fvec4 a0 = {acc[i][0], acc[i][1], acc[i][2], acc[i][3]};
      fvec4 a1 = {acc[i][4], acc[i][5], acc[i][6], acc[i][7]};
      *(fvec4*)&red[(w * SS + i) * DD + lane * 8] = a0;
      *(fvec4*)&red[(w * SS + i) * DD + lane * 8 + 4] = a1;
    }
  }
  __syncthreads();
  int i2 = t >> 5, dsg = (t & 31) * 8;
  float* up = upart + ((size_t)(b * 16 + chunk)) * (SS * DD) + i2 * DD + dsg;
#pragma unroll
  for (int e = 0; e < 8; e++)
    up[e] = red[(0 * SS + i2) * DD + dsg + e] + red[(1 * SS + i2) * DD + dsg + e] +
            red[(2 * SS + i2) * DD + dsg + e] + red[(3 * SS + i2) * DD + dsg + e];
}

// ---------------- I4a: sn = slots + sum(upart)/colsum; LN -> h; h2 = relu(h@W1+b1) slice ----------------
__launch_bounds__(256)
__global__ void k_mlp1(const float* __restrict__ slots, const float* __restrict__ colsum,
                       const float* __restrict__ upart, const float* __restrict__ g_m,
                       const float* __restrict__ b_m, const float* __restrict__ W1,
                       const float* __restrict__ b1, float* __restrict__ h2g,
                       float* __restrict__ snbuf) {
  __shared__ float hL[SS][DD];
  __shared__ float part[4][SS][64];
  int b = blockIdx.x, cg = blockIdx.y, t = threadIdx.x;
  int row = t >> 5, seg = t & 31;
  {
    float inv = 1.0f / (colsum[b * SS + row] + EPS_ATTN);
    const float* sp = slots + (size_t)(b * SS + row) * DD + seg * 8;
    float u[8] = {};
    for (int c = 0; c < 16; c++) {
      const float* up = upart + ((size_t)(b * 16 + c)) * (SS * DD) + row * DD + seg * 8;
      fvec4 u0 = *(const fvec4*)up;
      fvec4 u1 = *(const fvec4*)(up + 4);
      u[0] += u0.x; u[1] += u0.y; u[2] += u0.z; u[3] += u0.w;
      u[4] += u1.x; u[5] += u1.y; u[6] += u1.z; u[7] += u1.w;
    }
    float v[8];
    float s = 0.f, s2 = 0.f;
#pragma unroll
    for (int e = 0; e < 8; e++) {
      v[e] = sp[e] + u[e] * inv;
      s += v[e]; s2 += v[e] * v[e];
    }
    if (cg == 0) {
      float* snp = snbuf + (size_t)(b * SS + row) * DD + seg * 8;
#pragma unroll
      for (int e = 0; e < 8; e++) snp[e] = v[e];
    }
#pragma unroll
    for (int m = 16; m >= 1; m >>= 1) { s += __shfl_xor(s, m); s2 += __shfl_xor(s2, m); }
    float mu = s / DD;
    float rs = rsqrtf(s2 / DD - mu * mu + EPS_LN);
#pragma unroll
    for (int e = 0; e < 8; e++) {
      int d = seg * 8 + e;
      hL[row][d] = (v[e] - mu) * rs * g_m[d] + b_m[d];
    }
  }
  __syncthreads();
  int kq = t >> 6, c = t & 63;
  int colg = cg * 64 + c;
  float a[SS] = {};
  for (int kk = 0; kk < 64; kk++) {
    int k = kq * 64 + kk;
    float wv = W1[k * DD + colg];
#pragma unroll
    for (int i = 0; i < SS; i++) a[i] += hL[i][k] * wv;
  }
#pragma unroll
  for (int i = 0; i < SS; i++) part[kq][i][c] = a[i];
  __syncthreads();
  int i0 = t >> 6;
#pragma unroll
  for (int ii = 0; ii < 2; ii++) {
    int i = i0 + ii * 4;
    float s = part[0][i][c] + part[1][i][c] + part[2][i][c] + part[3][i][c];
    h2g[(size_t)(b * SS + i) * DD + colg] = fmaxf(s + b1[colg], 0.f);
  }
}

// ---------------- I4b: slots = sn + h2@W2 + b2 (slice) ----------------
__launch_bounds__(256)
__global__ void k_mlp2(float* __restrict__ slots, const float* __restrict__ snbuf,
                       const float* __restrict__ h2g, const float* __restrict__ W2,
                       const float* __restrict__ b2) {
  __shared__ float h2L[SS][DD];
  __shared__ float part[4][SS][64];
  int b = blockIdx.x, cg = blockIdx.y, t = threadIdx.x;
  {
    const fvec4* src = (const fvec4*)(h2g + (size_t)b * SS * DD);
    fvec4* dst = (fvec4*)h2L;
    for (int j = t; j < SS * DD / 4; j += 256) dst[j] = src[j];
  }
  __syncthreads();
  int kq = t >> 6, c = t & 63;
  int colg = cg * 64 + c;
  float a[SS] = {};
  for (int kk = 0; kk < 64; kk++) {
    int k = kq * 64 + kk;
    float wv = W2[k * DD + colg];
#pragma unroll
    for (int i = 0; i < SS; i++) a[i] += h2L[i][k] * wv;
  }
#pragma unroll
  for (int i = 0; i < SS; i++) part[kq][i][c] = a[i];
  __syncthreads();
  int i0 = t >> 6;
#pragma unroll
  for (int ii = 0; ii < 2; ii++) {
    int i = i0 + ii * 4;
    float s = part[0][i][c] + part[1][i][c] + part[2][i][c] + part[3][i][c];
    size_t idx = (size_t)(b * SS + i) * DD + colg;
    slots[idx] = snbuf[idx] + s + b2[colg];
  }
}

// ---------------- final LN -> out ----------------
__launch_bounds__(256)
__global__ void k_out(const float* __restrict__ slots, const float* __restrict__ g_o,
                      const float* __restrict__ b_o, float* __restrict__ out) {
  int b = blockIdx.x, t = threadIdx.x;
  int row = t >> 5, seg = t & 31;
  const float* sp = slots + (size_t)(b * SS + row) * DD + seg * 8;
  float v[8];
  float s = 0.f, s2 = 0.f;
#pragma unroll
  for (int e = 0; e < 8; e++) { v[e] = sp[e]; s += v[e]; s2 += v[e] * v[e]; }
#pragma unroll
  for (int m = 16; m >= 1; m >>= 1) { s += __shfl_xor(s, m); s2 += __shfl_xor(s2, m); }
  float mu = s / DD;
  float rs = rsqrtf(s2 / DD - mu * mu + EPS_LN);
#pragma unroll
  for (int e = 0; e < 8; e++) {
    int d = seg * 8 + e;
    out[(size_t)(b * SS + row) * DD + d] = (v[e] - mu) * rs * g_o[d] + b_o[d];
  }
}

extern "C" void kernel_launch(void* const* d_in, const int* in_sizes, int n_in,
                              void* d_out, int out_size, void* d_ws, size_t ws_size,
                              hipStream_t stream) {
  (void)in_sizes; (void)n_in; (void)out_size; (void)ws_size;
  const float* inputs = (const float*)d_in[0];
  const int* mask = (const int*)d_in[1];
  const float* slots_init = (const float*)d_in[2];
  const float* g_in = (const float*)d_in[3];
  const float* b_in = (const float*)d_in[4];
  const float* g_s = (const float*)d_in[5];
  const float* b_s = (const float*)d_in[6];
  const float* g_m = (const float*)d_in[7];
  const float* b_m = (const float*)d_in[8];
  const float* g_o = (const float*)d_in[9];
  const float* b_o = (const float*)d_in[10];
  const float* Wq = (const float*)d_in[11];
  const float* bq = (const float*)d_in[12];
  const float* Wk = (const float*)d_in[13];
  const float* bk = (const float*)d_in[14];
  const float* Wv = (const float*)d_in[15];
  const float* bv = (const float*)d_in[16];
  const float* W1 = (const float*)d_in[17];
  const float* b1 = (const float*)d_in[18];
  const float* W2 = (const float*)d_in[19];
  const float* b2 = (const float*)d_in[20];
  float* out = (float*)d_out;

  char* ws = (char*)d_ws;
  size_t off = 0;
  auto alloc = [&](size_t bytes) -> void* {
    void* p = ws + off;
    off += (bytes + 255) & ~(size_t)255;
    return p;
  };
  unsigned short* kbf = (unsigned short*)alloc((size_t)BB * NN * DD * 2);
  unsigned short* vbf = (unsigned short*)alloc((size_t)BB * NN * DD * 2);
  unsigned short* wkvf = (unsigned short*)alloc((size_t)2 * DD * DD * 2);
  float* q = (float*)alloc((size_t)BB * SS * DD * 4);
  float* slots = (float*)alloc((size_t)BB * SS * DD * 4);
  float* snbuf = (float*)alloc((size_t)BB * SS * DD * 4);
  float* h2g = (float*)alloc((size_t)BB * SS * DD * 4);
  float* upart = (float*)alloc((size_t)BB * 16 * SS * DD * 4);
  float* colsum = (float*)alloc((size_t)BB * SS * 4);

  k_sinit<<<dim3(BB), dim3(256), 0, stream>>>(slots_init, slots);
  k_wprepf<<<dim3(32, 8), dim3(64), 0, stream>>>(Wk, Wv, wkvf);
  k_lngemm<<<dim3(BB * NN / 128), dim3(512), 0, stream>>>(inputs, g_in, b_in, wkvf, bk, bv, kbf, vbf);

  for (int it = 0; it < NITER; ++it) {
    k_slotq<<<dim3(BB, 4), dim3(256), 0, stream>>>(slots, g_s, b_s, Wq, bq, q, colsum);
    k_attn<<<dim3(16, BB), dim3(256), 0, stream>>>(kbf, vbf, q, mask, colsum, upart);
    k_mlp1<<<dim3(BB, 4), dim3(256), 0, stream>>>(slots, colsum, upart, g_m, b_m, W1, b1, h2g, snbuf);
    k_mlp2<<<dim3(BB, 4), dim3(256), 0, stream>>>(slots, snbuf, h2g, W2, b2);
  }
  k_out<<<dim3(BB), dim3(256), 0, stream>>>(slots, g_o, b_o, out);
}

// Round 5
// 628.162 us; speedup vs baseline: 1.3055x; 1.0931x over previous
//
#include <hip/hip_runtime.h>
#include <stdint.h>

#define BB 64
#define NN 4096
#define DD 256
#define SS 8
#define NITER 3
#define EPS_LN 1e-5f
#define EPS_ATTN 1e-8f

typedef __attribute__((ext_vector_type(4))) float fvec4;
typedef __attribute__((ext_vector_type(8))) __bf16 bf16x8;
typedef __attribute__((ext_vector_type(8))) unsigned short usvec8;
typedef __attribute__((ext_vector_type(4))) unsigned short usvec4;

__device__ __forceinline__ float bf2f(unsigned short u) {
  return __uint_as_float(((unsigned)u) << 16);
}
__device__ __forceinline__ unsigned short f2bf(float f) {
  unsigned u = __float_as_uint(f);
  u += 0x7FFFu + ((u >> 16) & 1u);
  return (unsigned short)(u >> 16);
}
__device__ __forceinline__ void async_copy16(void* ldsp, const void* gp) {
  __builtin_amdgcn_global_load_lds(
      (const __attribute__((address_space(1))) unsigned int*)gp,
      (__attribute__((address_space(3))) unsigned int*)ldsp, 16, 0, 0);
}

// ---------------- init: slots broadcast ----------------
__global__ void k_sinit(const float* __restrict__ slots_init, float* __restrict__ slots) {
  int b = blockIdx.x, t = threadIdx.x;
  const fvec4* src = (const fvec4*)slots_init;
  fvec4* dst = (fvec4*)(slots + (size_t)b * SS * DD);
  for (int j = t; j < SS * DD / 4; j += 256) dst[j] = src[j];
}

// ---------------- init: fragment-major packed weights ----------------
// wkvf[((ct*8 + ks)*64 + lane)*8 + e] = bf16( B[col=ct*16+(lane&15)][k=ks*32+(lane>>4)*8+e] )
// where B[col][k] = (col<256 ? Wk : Wv)[k][col&255]
__global__ void k_wprepf(const float* __restrict__ Wk, const float* __restrict__ Wv,
                         unsigned short* __restrict__ wkvf) {
  int ct = blockIdx.x, ks = blockIdx.y, t = threadIdx.x;
  int col = ct * 16 + (t & 15);
  int kb = ks * 32 + (t >> 4) * 8;
  const float* W = (col < DD) ? Wk : Wv;
  int cc = col & (DD - 1);
  usvec8 o;
#pragma unroll
  for (int e = 0; e < 8; e++) o[e] = f2bf(W[(size_t)(kb + e) * DD + cc]);
  *(usvec8*)&wkvf[(((size_t)ct * 8 + ks) * 64 + t) * 8] = o;
}

// ---------------- A: fused LN + GEMM, 64-row tile, 256 thr, 3 blocks/CU ----------------
__launch_bounds__(256, 3)
__global__ void k_lngemm(const float* __restrict__ in, const float* __restrict__ g,
                         const float* __restrict__ bt, const unsigned short* __restrict__ wkvf,
                         const float* __restrict__ bk, const float* __restrict__ bv,
                         unsigned short* __restrict__ kout, unsigned short* __restrict__ vout) {
  __shared__ __attribute__((aligned(16))) unsigned short lA[64 * 256];        // 32 KB swizzled
  __shared__ __attribute__((aligned(16))) unsigned short episcr[4][64 * 36];  // 18.4 KB
  int t = threadIdx.x;
  int w = t >> 6, lane = t & 63;
  int cl15 = lane & 15, rg = lane >> 4;
  long bm = blockIdx.x;

  // ---- phase 1: LN of 64 input rows -> swizzled bf16 A-tile in LDS ----
#pragma unroll
  for (int pass = 0; pass < 2; pass++) {
    int row = pass * 32 + (t >> 3);
    int u = t & 7;
    const float* rp = in + (bm * 64 + row) * DD;
    fvec4 vv[8];
    float s = 0.f, s2 = 0.f;
#pragma unroll
    for (int j = 0; j < 8; j++) {
      vv[j] = *(const fvec4*)(rp + j * 32 + u * 4);
      s += vv[j].x + vv[j].y + vv[j].z + vv[j].w;
      s2 += vv[j].x * vv[j].x + vv[j].y * vv[j].y + vv[j].z * vv[j].z + vv[j].w * vv[j].w;
    }
    s += __shfl_xor(s, 1); s2 += __shfl_xor(s2, 1);
    s += __shfl_xor(s, 2); s2 += __shfl_xor(s2, 2);
    s += __shfl_xor(s, 4); s2 += __shfl_xor(s2, 4);
    float mu = s / DD;
    float rs = rsqrtf(s2 / DD - mu * mu + EPS_LN);
#pragma unroll
    for (int j = 0; j < 8; j++) {
      fvec4 gg = *(const fvec4*)(g + j * 32 + u * 4);
      fvec4 bb = *(const fvec4*)(bt + j * 32 + u * 4);
      usvec4 o;
      o[0] = f2bf((vv[j].x - mu) * rs * gg.x + bb.x);
      o[1] = f2bf((vv[j].y - mu) * rs * gg.y + bb.y);
      o[2] = f2bf((vv[j].z - mu) * rs * gg.z + bb.z);
      o[3] = f2bf((vv[j].w - mu) * rs * gg.w + bb.w);
      int gswz = (j * 4 + (u >> 1)) ^ (row & 7);
      *(usvec4*)&lA[row * 256 + gswz * 8 + (u & 1) * 4] = o;
    }
  }
  __syncthreads();

  // ---- phase 2: MFMA over K=256; wave w -> cols w*64..w*64+63; cn=0 k, cn=1 v ----
  unsigned short* epi = &episcr[w][0];
#pragma unroll
  for (int cn = 0; cn < 2; cn++) {
    fvec4 acc[4][4] = {};
#pragma unroll
    for (int ks = 0; ks < 8; ks++) {
      bf16x8 af[4], bfr[4];
#pragma unroll
      for (int m = 0; m < 4; m++) {
        int row = m * 16 + cl15;
        int gr = (ks * 4 + rg) ^ (row & 7);
        af[m] = *(const bf16x8*)&lA[row * 256 + gr * 8];
      }
#pragma unroll
      for (int n = 0; n < 4; n++) {
        int ct = cn * 16 + w * 4 + n;
        bfr[n] = *(const bf16x8*)&wkvf[(((size_t)ct * 8 + ks) * 64 + lane) * 8];
      }
#pragma unroll
      for (int m = 0; m < 4; m++)
#pragma unroll
        for (int n = 0; n < 4; n++)
          acc[m][n] = __builtin_amdgcn_mfma_f32_16x16x32_bf16(af[m], bfr[n], acc[m][n], 0, 0, 0);
    }
    // epilogue: per-wave LDS transpose -> coalesced 64B-sector stores
    const float* bsrc = cn ? bv : bk;
    unsigned short* op = cn ? vout : kout;
    float biasv[4];
#pragma unroll
    for (int n = 0; n < 4; n++) biasv[n] = bsrc[w * 64 + n * 16 + cl15];
#pragma unroll
    for (int h = 0; h < 2; h++) {
#pragma unroll
      for (int n2 = 0; n2 < 2; n2++) {
        int n = h * 2 + n2;
#pragma unroll
        for (int m = 0; m < 4; m++)
#pragma unroll
          for (int e = 0; e < 4; e++)
            epi[(m * 16 + rg * 4 + e) * 36 + n2 * 16 + cl15] = f2bf(acc[m][n][e] + biasv[n]);
      }
      asm volatile("s_waitcnt lgkmcnt(0)" ::: "memory");
      __builtin_amdgcn_sched_barrier(0);
      int rl = lane >> 3, u = lane & 7;
#pragma unroll
      for (int r8 = 0; r8 < 8; r8++) {
        int row_l = r8 * 8 + rl;
        usvec4 vv = *(const usvec4*)&epi[row_l * 36 + u * 4];
        *(usvec4*)&op[(bm * 64 + row_l) * DD + w * 64 + h * 32 + u * 4] = vv;
      }
      asm volatile("s_waitcnt lgkmcnt(0)" ::: "memory");
      __builtin_amdgcn_sched_barrier(0);
    }
  }
}

// ---------------- I1: s = LN(slots); q = (s@Wq + bq) * D^-0.5 ; zero colsum ----------------
__launch_bounds__(256)
__global__ void k_slotq(const float* __restrict__ slots, const float* __restrict__ g_s,
                        const float* __restrict__ b_s, const float* __restrict__ Wq,
                        const float* __restrict__ bq, float* __restrict__ qout,
                        float* __restrict__ colsum) {
  __shared__ float sl[SS][DD];
  __shared__ float part[4][SS][64];
  int b = blockIdx.x, cg = blockIdx.y, t = threadIdx.x;
  if (cg == 0 && t < SS) colsum[b * SS + t] = 0.f;
  int row = t >> 5, seg = t & 31;
  {
    const float* sp = slots + (size_t)(b * SS + row) * DD + seg * 8;
    float v[8];
    float s = 0.f, s2 = 0.f;
#pragma unroll
    for (int e = 0; e < 8; e++) { v[e] = sp[e]; s += v[e]; s2 += v[e] * v[e]; }
#pragma unroll
    for (int m = 16; m >= 1; m >>= 1) { s += __shfl_xor(s, m); s2 += __shfl_xor(s2, m); }
    float mu = s / DD;
    float rs = rsqrtf(s2 / DD - mu * mu + EPS_LN);
#pragma unroll
    for (int e = 0; e < 8; e++) {
      int d = seg * 8 + e;
      sl[row][d] = (v[e] - mu) * rs * g_s[d] + b_s[d];
    }
  }
  __syncthreads();
  int kq = t >> 6, c = t & 63;
  int colg = cg * 64 + c;
  float a[SS] = {};
  for (int kk = 0; kk < 64; kk++) {
    int k = kq * 64 + kk;
    float wv = Wq[k * DD + colg];
#pragma unroll
    for (int i = 0; i < SS; i++) a[i] += sl[i][k] * wv;
  }
#pragma unroll
  for (int i = 0; i < SS; i++) part[kq][i][c] = a[i];
  __syncthreads();
  int i0 = t >> 6;
#pragma unroll
  for (int ii = 0; ii < 2; ii++) {
    int i = i0 + ii * 4;
    float s = part[0][i][c] + part[1][i][c] + part[2][i][c] + part[3][i][c];
    qout[(size_t)(b * SS + i) * DD + colg] = (s + bq[colg]) * 0.0625f;
  }
}

// ---------------- I2+I3: MFMA QK^T (LDS-staged k) -> slot-softmax -> VALU PV ----------------
__launch_bounds__(256, 2)
__global__ void k_attn(const unsigned short* __restrict__ kbf,
                       const unsigned short* __restrict__ vbf,
                       const float* __restrict__ qs, const int* __restrict__ mask,
                       float* __restrict__ colsum, float* __restrict__ upart) {
  __shared__ __attribute__((aligned(16))) unsigned short kt[2][64 * 256];  // 2x32KB swizzled
  __shared__ float aL[2][64 * 9];                                          // attn weights
  int b = blockIdx.y, chunk = blockIdx.x, t = threadIdx.x;
  int w = t >> 6, lane = t & 63;
  int n_base = chunk * 256;
  int cl15 = lane & 15, hg = lane >> 4;

  // ---- q A-fragments (bf16), slots 8..15 zero ----
  bf16x8 qf[8];
  {
    int qrow = cl15 < 8 ? cl15 : 0;
    const float* qp = qs + (size_t)(b * SS + qrow) * DD;
#pragma unroll
    for (int kst = 0; kst < 8; kst++) {
      int d0 = kst * 32 + hg * 8;
      usvec8 uq;
      if (cl15 < 8) {
        fvec4 q0 = *(const fvec4*)(qp + d0);
        fvec4 q1 = *(const fvec4*)(qp + d0 + 4);
        uq[0] = f2bf(q0.x); uq[1] = f2bf(q0.y); uq[2] = f2bf(q0.z); uq[3] = f2bf(q0.w);
        uq[4] = f2bf(q1.x); uq[5] = f2bf(q1.y); uq[6] = f2bf(q1.z); uq[7] = f2bf(q1.w);
      } else {
        uq = (usvec8)0;
      }
      qf[kst] = __builtin_bit_cast(bf16x8, uq);
    }
  }

  float acc[SS][8] = {};   // PV accumulators: [slot][d-elem]
  float csum[4] = {};      // colsum partials (lanes<32)
  int ns = t >> 5, dl = (t & 31) * 8;  // phase-2 stream mapping

  // stage sub-chunk c into buf bb: wave w stages rows w*16..w*16+15 (self-staged)
  auto stage = [&](int c, int bb) {
    int r0 = n_base + c * 64;
#pragma unroll
    for (int j = 0; j < 8; j++) {
      int gidx = w * 512 + j * 64 + lane;
      int row = gidx >> 5, c16 = gidx & 31;
      async_copy16(&kt[bb][gidx * 8],
                   kbf + ((size_t)(b * NN + r0 + row)) * DD + ((c16 ^ (row & 7)) * 8));
    }
  };

  stage(0, 0);
  for (int c = 0; c < 4; c++) {
    int bb = c & 1, pb = c & 1;
    int r0 = n_base + c * 64;
    if (c < 3) {
      stage(c + 1, bb ^ 1);
      asm volatile("s_waitcnt vmcnt(8)" ::: "memory");
    } else {
      asm volatile("s_waitcnt vmcnt(0)" ::: "memory");
    }
    __builtin_amdgcn_sched_barrier(0);
    // ---- QK^T: wave w's 16-n tile (rows w*16..+15 of this sub-chunk) ----
    fvec4 S = {0.f, 0.f, 0.f, 0.f};
    int row_l = w * 16 + cl15;
#pragma unroll
    for (int kst = 0; kst < 8; kst++) {
      int c16 = (kst * 4 + hg) ^ (row_l & 7);
      bf16x8 bfk = *(const bf16x8*)&kt[bb][row_l * 256 + c16 * 8];
      S = __builtin_amdgcn_mfma_f32_16x16x32_bf16(qf[kst], bfk, S, 0, 0, 0);
    }
    // ---- per-n softmax over 8 slots (lane&15 = n, hg in {0,1} = slot half) ----
    {
      float m4 = fmaxf(fmaxf(S[0], S[1]), fmaxf(S[2], S[3]));
      float mo = __shfl_xor(m4, 16);
      float mx = fmaxf(m4, mo);
      float e0 = __expf(S[0] - mx), e1 = __expf(S[1] - mx);
      float e2 = __expf(S[2] - mx), e3 = __expf(S[3] - mx);
      float s4 = e0 + e1 + e2 + e3;
      float so = __shfl_xor(s4, 16);
      float inv = 1.f / (s4 + so);
      int mk = mask[(size_t)b * NN + r0 + row_l];
      float a0 = mk ? 0.125f : e0 * inv;
      float a1 = mk ? 0.125f : e1 * inv;
      float a2 = mk ? 0.125f : e2 * inv;
      float a3 = mk ? 0.125f : e3 * inv;
      if (lane < 32) {
        csum[0] += a0; csum[1] += a1; csum[2] += a2; csum[3] += a3;
        float* ap = &aL[pb][(w * 16 + cl15) * 9 + hg * 4];
        ap[0] = a0; ap[1] = a1; ap[2] = a2; ap[3] = a3;
      }
    }
    __syncthreads();
    // ---- phase 2: PV (coalesced global v reads, aL broadcast reads) ----
    const unsigned short* vb = vbf + ((size_t)(b * NN + r0 + ns)) * DD + dl;
#pragma unroll
    for (int s8 = 0; s8 < 8; s8++) {
      int nn = s8 * 8;
      usvec8 vv = *(const usvec8*)(vb + (size_t)nn * DD);
      float vf[8];
#pragma unroll
      for (int e = 0; e < 8; e++) vf[e] = bf2f(vv[e]);
#pragma unroll
      for (int i = 0; i < SS; i++) {
        float aw = aL[pb][(ns + nn) * 9 + i];
#pragma unroll
        for (int e = 0; e < 8; e++) acc[i][e] += aw * vf[e];
      }
    }
  }
  // ---- colsum reduce + atomics ----
#pragma unroll
  for (int m = 1; m <= 8; m <<= 1)
#pragma unroll
    for (int e = 0; e < 4; e++) csum[e] += __shfl_xor(csum[e], m);
  if (lane == 0) {
#pragma unroll
    for (int e = 0; e < 4; e++) atomicAdd(&colsum[b * SS + e], csum[e]);
  } else if (lane == 16) {
#pragma unroll
    for (int e = 0; e < 4; e++) atomicAdd(&colsum[b * SS + 4 + e], csum[e]);
  }
  // ---- cross-stream + cross-wave reduce of PV accumulators (reuse kt as scratch) ----
#pragma unroll
  for (int i = 0; i < SS; i++)
#pragma unroll
    for (int e = 0; e < 8; e++) acc[i][e] += __shfl_xor(acc[i][e], 32);
  __syncthreads();
  float* red = (float*)&kt[0][0];  // [4][SS][DD]
  if (lane < 32) {
#pragma unroll
    for (int i = 0; i < SS; i++) {
      fvec4 a0 = {acc[i][0], acc[i][1], acc[i][2], acc[i][3]};
      fvec4 a1 = {acc[i][4], acc[i][5], acc[i][6], acc[i][7]};
      *(fvec4*)&red[(w * SS + i) * DD + lane * 8] = a0;
      *(fvec4*)&red[(w * SS + i) * DD + lane * 8 + 4] = a1;
    }
  }
  __syncthreads();
  int i2 = t >> 5, dsg = (t & 31) * 8;
  float* up = upart + ((size_t)(b * 16 + chunk)) * (SS * DD) + i2 * DD + dsg;
#pragma unroll
  for (int e = 0; e < 8; e++)
    up[e] = red[(0 * SS + i2) * DD + dsg + e] + red[(1 * SS + i2) * DD + dsg + e] +
            red[(2 * SS + i2) * DD + dsg + e] + red[(3 * SS + i2) * DD + dsg + e];
}

// ---------------- I4a: sn = slots + sum(upart)/colsum; LN -> h; h2 = relu(h@W1+b1) slice ----------------
__launch_bounds__(256)
__global__ void k_mlp1(const float* __restrict__ slots, const float* __restrict__ colsum,
                       const float* __restrict__ upart, const float* __restrict__ g_m,
                       const float* __restrict__ b_m, const float* __restrict__ W1,
                       const float* __restrict__ b1, float* __restrict__ h2g,
                       float* __restrict__ snbuf) {
  __shared__ float hL[SS][DD];
  __shared__ float part[4][SS][64];
  int b = blockIdx.x, cg = blockIdx.y, t = threadIdx.x;
  int row = t >> 5, seg = t & 31;
  {
    float inv = 1.0f / (colsum[b * SS + row] + EPS_ATTN);
    const float* sp = slots + (size_t)(b * SS + row) * DD + seg * 8;
    float u[8] = {};
    for (int c = 0; c < 16; c++) {
      const float* up = upart + ((size_t)(b * 16 + c)) * (SS * DD) + row * DD + seg * 8;
      fvec4 u0 = *(const fvec4*)up;
      fvec4 u1 = *(const fvec4*)(up + 4);
      u[0] += u0.x; u[1] += u0.y; u[2] += u0.z; u[3] += u0.w;
      u[4] += u1.x; u[5] += u1.y; u[6] += u1.z; u[7] += u1.w;
    }
    float v[8];
    float s = 0.f, s2 = 0.f;
#pragma unroll
    for (int e = 0; e < 8; e++) {
      v[e] = sp[e] + u[e] * inv;
      s += v[e]; s2 += v[e] * v[e];
    }
    if (cg == 0) {
      float* snp = snbuf + (size_t)(b * SS + row) * DD + seg * 8;
#pragma unroll
      for (int e = 0; e < 8; e++) snp[e] = v[e];
    }
#pragma unroll
    for (int m = 16; m >= 1; m >>= 1) { s += __shfl_xor(s, m); s2 += __shfl_xor(s2, m); }
    float mu = s / DD;
    float rs = rsqrtf(s2 / DD - mu * mu + EPS_LN);
#pragma unroll
    for (int e = 0; e < 8; e++) {
      int d = seg * 8 + e;
      hL[row][d] = (v[e] - mu) * rs * g_m[d] + b_m[d];
    }
  }
  __syncthreads();
  int kq = t >> 6, c = t & 63;
  int colg = cg * 64 + c;
  float a[SS] = {};
  for (int kk = 0; kk < 64; kk++) {
    int k = kq * 64 + kk;
    float wv = W1[k * DD + colg];
#pragma unroll
    for (int i = 0; i < SS; i++) a[i] += hL[i][k] * wv;
  }
#pragma unroll
  for (int i = 0; i < SS; i++) part[kq][i][c] = a[i];
  __syncthreads();
  int i0 = t >> 6;
#pragma unroll
  for (int ii = 0; ii < 2; ii++) {
    int i = i0 + ii * 4;
    float s = part[0][i][c] + part[1][i][c] + part[2][i][c] + part[3][i][c];
    h2g[(size_t)(b * SS + i) * DD + colg] = fmaxf(s + b1[colg], 0.f);
  }
}

// ---------------- I4b: slots = sn + h2@W2 + b2 (slice) ----------------
__launch_bounds__(256)
__global__ void k_mlp2(float* __restrict__ slots, const float* __restrict__ snbuf,
                       const float* __restrict__ h2g, const float* __restrict__ W2,
                       const float* __restrict__ b2) {
  __shared__ float h2L[SS][DD];
  __shared__ float part[4][SS][64];
  int b = blockIdx.x, cg = blockIdx.y, t = threadIdx.x;
  {
    const fvec4* src = (const fvec4*)(h2g + (size_t)b * SS * DD);
    fvec4* dst = (fvec4*)h2L;
    for (int j = t; j < SS * DD / 4; j += 256) dst[j] = src[j];
  }
  __syncthreads();
  int kq = t >> 6, c = t & 63;
  int colg = cg * 64 + c;
  float a[SS] = {};
  for (int kk = 0; kk < 64; kk++) {
    int k = kq * 64 + kk;
    float wv = W2[k * DD + colg];
#pragma unroll
    for (int i = 0; i < SS; i++) a[i] += h2L[i][k] * wv;
  }
#pragma unroll
  for (int i = 0; i < SS; i++) part[kq][i][c] = a[i];
  __syncthreads();
  int i0 = t >> 6;
#pragma unroll
  for (int ii = 0; ii < 2; ii++) {
    int i = i0 + ii * 4;
    float s = part[0][i][c] + part[1][i][c] + part[2][i][c] + part[3][i][c];
    size_t idx = (size_t)(b * SS + i) * DD + colg;
    slots[idx] = snbuf[idx] + s + b2[colg];
  }
}

// ---------------- final LN -> out ----------------
__launch_bounds__(256)
__global__ void k_out(const float* __restrict__ slots, const float* __restrict__ g_o,
                      const float* __restrict__ b_o, float* __restrict__ out) {
  int b = blockIdx.x, t = threadIdx.x;
  int row = t >> 5, seg = t & 31;
  const float* sp = slots + (size_t)(b * SS + row) * DD + seg * 8;
  float v[8];
  float s = 0.f, s2 = 0.f;
#pragma unroll
  for (int e = 0; e < 8; e++) { v[e] = sp[e]; s += v[e]; s2 += v[e] * v[e]; }
#pragma unroll
  for (int m = 16; m >= 1; m >>= 1) { s += __shfl_xor(s, m); s2 += __shfl_xor(s2, m); }
  float mu = s / DD;
  float rs = rsqrtf(s2 / DD - mu * mu + EPS_LN);
#pragma unroll
  for (int e = 0; e < 8; e++) {
    int d = seg * 8 + e;
    out[(size_t)(b * SS + row) * DD + d] = (v[e] - mu) * rs * g_o[d] + b_o[d];
  }
}

extern "C" void kernel_launch(void* const* d_in, const int* in_sizes, int n_in,
                              void* d_out, int out_size, void* d_ws, size_t ws_size,
                              hipStream_t stream) {
  (void)in_sizes; (void)n_in; (void)out_size; (void)ws_size;
  const float* inputs = (const float*)d_in[0];
  const int* mask = (const int*)d_in[1];
  const float* slots_init = (const float*)d_in[2];
  const float* g_in = (const float*)d_in[3];
  const float* b_in = (const float*)d_in[4];
  const float* g_s = (const float*)d_in[5];
  const float* b_s = (const float*)d_in[6];
  const float* g_m = (const float*)d_in[7];
  const float* b_m = (const float*)d_in[8];
  const float* g_o = (const float*)d_in[9];
  const float* b_o = (const float*)d_in[10];
  const float* Wq = (const float*)d_in[11];
  const float* bq = (const float*)d_in[12];
  const float* Wk = (const float*)d_in[13];
  const float* bk = (const float*)d_in[14];
  const float* Wv = (const float*)d_in[15];
  const float* bv = (const float*)d_in[16];
  const float* W1 = (const float*)d_in[17];
  const float* b1 = (const float*)d_in[18];
  const float* W2 = (const float*)d_in[19];
  const float* b2 = (const float*)d_in[20];
  float* out = (float*)d_out;

  char* ws = (char*)d_ws;
  size_t off = 0;
  auto alloc = [&](size_t bytes) -> void* {
    void* p = ws + off;
    off += (bytes + 255) & ~(size_t)255;
    return p;
  };
  unsigned short* kbf = (unsigned short*)alloc((size_t)BB * NN * DD * 2);
  unsigned short* vbf = (unsigned short*)alloc((size_t)BB * NN * DD * 2);
  unsigned short* wkvf = (unsigned short*)alloc((size_t)2 * DD * DD * 2);
  float* q = (float*)alloc((size_t)BB * SS * DD * 4);
  float* slots = (float*)alloc((size_t)BB * SS * DD * 4);
  float* snbuf = (float*)alloc((size_t)BB * SS * DD * 4);
  float* h2g = (float*)alloc((size_t)BB * SS * DD * 4);
  float* upart = (float*)alloc((size_t)BB * 16 * SS * DD * 4);
  float* colsum = (float*)alloc((size_t)BB * SS * 4);

  k_sinit<<<dim3(BB), dim3(256), 0, stream>>>(slots_init, slots);
  k_wprepf<<<dim3(32, 8), dim3(64), 0, stream>>>(Wk, Wv, wkvf);
  k_lngemm<<<dim3(BB * NN / 64), dim3(256), 0, stream>>>(inputs, g_in, b_in, wkvf, bk, bv, kbf, vbf);

  for (int it = 0; it < NITER; ++it) {
    k_slotq<<<dim3(BB, 4), dim3(256), 0, stream>>>(slots, g_s, b_s, Wq, bq, q, colsum);
    k_attn<<<dim3(16, BB), dim3(256), 0, stream>>>(kbf, vbf, q, mask, colsum, upart);
    k_mlp1<<<dim3(BB, 4), dim3(256), 0, stream>>>(slots, colsum, upart, g_m, b_m, W1, b1, h2g, snbuf);
    k_mlp2<<<dim3(BB, 4), dim3(256), 0, stream>>>(slots, snbuf, h2g, W2, b2);
  }
  k_out<<<dim3(BB), dim3(256), 0, stream>>>(slots, g_o, b_o, out);
}